// Round 2
// baseline (701.181 us; speedup 1.0000x reference)
//
#include <hip/hip_runtime.h>
#include <hip/hip_bf16.h>
#include <math.h>

// Problem constants (fixed shapes from the reference)
constexpr int B_  = 4;
constexpr int N_  = 10000;
constexpr int E_  = 160000;
constexpr int D_  = 128;
constexpr int H_  = 4;
constexpr int O_  = 64;
constexpr float NEG_SLOPE = 0.2f;

constexpr int NODES_PER_BLOCK = 16;   // 10000 % 16 == 0 -> 625 blocks per batch

// ---------------------------------------------------------------------------
// Kernel 1: h[b,n,h,o] = sum_d x[b,n,d] * W_src[d,h,o]
//           a_src[b,n,h] = sum_o h * att_src[h,o];  a_dst likewise.
// One block = 16 nodes of one batch. t in [0,256) -> (head = t>>6, o = t&63).
// ---------------------------------------------------------------------------
__global__ __launch_bounds__(256) void k_gemm(
    const float* __restrict__ x, const float* __restrict__ Wsrc,
    const float* __restrict__ att_src, const float* __restrict__ att_dst,
    float* __restrict__ hb, float* __restrict__ asrc, float* __restrict__ adst)
{
    __shared__ float xs[NODES_PER_BLOCK][D_];
    const int t = threadIdx.x;
    const int head = t >> 6, o = t & 63;
    const int blocks_per_batch = N_ / NODES_PER_BLOCK;   // 625
    const int b  = blockIdx.x / blocks_per_batch;
    const int n0 = (blockIdx.x % blocks_per_batch) * NODES_PER_BLOCK;

    const float* xrow = x + ((size_t)b * N_ + n0) * D_;  // 16*128 contiguous floats
    for (int i = t; i < NODES_PER_BLOCK * D_; i += 256)
        ((float*)xs)[i] = xrow[i];
    __syncthreads();

    float acc[NODES_PER_BLOCK];
#pragma unroll
    for (int i = 0; i < NODES_PER_BLOCK; ++i) acc[i] = 0.f;

    for (int d = 0; d < D_; d += 4) {
        float w0 = Wsrc[(size_t)(d + 0) * 256 + t];
        float w1 = Wsrc[(size_t)(d + 1) * 256 + t];
        float w2 = Wsrc[(size_t)(d + 2) * 256 + t];
        float w3 = Wsrc[(size_t)(d + 3) * 256 + t];
#pragma unroll
        for (int i = 0; i < NODES_PER_BLOCK; ++i) {
            float4 xv = *(const float4*)&xs[i][d];
            acc[i] = fmaf(xv.x, w0, acc[i]);
            acc[i] = fmaf(xv.y, w1, acc[i]);
            acc[i] = fmaf(xv.z, w2, acc[i]);
            acc[i] = fmaf(xv.w, w3, acc[i]);
        }
    }

    const float as_w = att_src[t];
    const float ad_w = att_dst[t];
#pragma unroll
    for (int i = 0; i < NODES_PER_BLOCK; ++i) {
        const int n = n0 + i;
        hb[(((size_t)b * N_ + n) * H_ + head) * O_ + o] = acc[i];
        float v1 = acc[i] * as_w;
        float v2 = acc[i] * ad_w;
#pragma unroll
        for (int off = 32; off > 0; off >>= 1) {
            v1 += __shfl_down(v1, off, 64);
            v2 += __shfl_down(v2, off, 64);
        }
        if (o == 0) {
            asrc[((size_t)b * N_ + n) * H_ + head] = v1;
            adst[((size_t)b * N_ + n) * H_ + head] = v2;
        }
    }
}

// ---------------------------------------------------------------------------
// Init: out <- bias broadcast, m <- -inf, s <- 0, c[h] = sum_o We[h,o]*ae[h,o]
// ---------------------------------------------------------------------------
__global__ void k_init(float* __restrict__ out, const float* __restrict__ bias,
                       float* __restrict__ m, float* __restrict__ s,
                       const float* __restrict__ W_edge,
                       const float* __restrict__ att_edge,
                       float* __restrict__ c)
{
    const int stride = gridDim.x * blockDim.x;
    const int idx = blockIdx.x * blockDim.x + threadIdx.x;
    const int total_out = B_ * N_ * O_;   // 2,560,000
    const int total_ms  = B_ * N_ * H_;   // 160,000
    for (int i = idx; i < total_out; i += stride) out[i] = bias[i & 63];
    for (int i = idx; i < total_ms; i += stride) { m[i] = -INFINITY; s[i] = 0.f; }
    if (blockIdx.x == 0) {
        float v = W_edge[threadIdx.x] * att_edge[threadIdx.x];
#pragma unroll
        for (int off = 32; off > 0; off >>= 1) v += __shfl_down(v, off, 64);
        if ((threadIdx.x & 63) == 0) c[threadIdx.x >> 6] = v;
    }
}

// ---------------------------------------------------------------------------
// Kernel A: per (e,b): alpha = leaky(a_src[src]+a_dst[dst]+ea*c), store,
//           atomicMax into m[dst,b,h].
// NOTE: edge_index arrives as int32 (harness converts int64 -> int).
// ---------------------------------------------------------------------------
__global__ __launch_bounds__(256) void k_logits(
    const int* __restrict__ ei, const float* __restrict__ eattr,
    const float* __restrict__ asrc, const float* __restrict__ adst,
    const float* __restrict__ c, float* __restrict__ palpha, float* __restrict__ m)
{
    const int tid = blockIdx.x * 256 + threadIdx.x;   // tid = e*B + b
    const int e = tid >> 2;
    const int b = tid & 3;
    const int src = ei[e];
    const int dst = ei[E_ + e];
    const float ea = eattr[e];
    float4 as = *(const float4*)&asrc[((size_t)b * N_ + src) * 4];
    float4 ad = *(const float4*)&adst[((size_t)b * N_ + dst) * 4];
    float4 cc = *(const float4*)c;
    float4 al;
    al.x = as.x + ad.x + ea * cc.x;
    al.y = as.y + ad.y + ea * cc.y;
    al.z = as.z + ad.z + ea * cc.z;
    al.w = as.w + ad.w + ea * cc.w;
    al.x = al.x > 0.f ? al.x : NEG_SLOPE * al.x;
    al.y = al.y > 0.f ? al.y : NEG_SLOPE * al.y;
    al.z = al.z > 0.f ? al.z : NEG_SLOPE * al.z;
    al.w = al.w > 0.f ? al.w : NEG_SLOPE * al.w;
    *(float4*)&palpha[(size_t)tid * 4] = al;
    float* mp = &m[((size_t)b * N_ + dst) * 4];
    atomicMax(&mp[0], al.x);
    atomicMax(&mp[1], al.y);
    atomicMax(&mp[2], al.z);
    atomicMax(&mp[3], al.w);
}

// ---------------------------------------------------------------------------
// Kernel B: p = exp(alpha - m[dst]); store p in place; atomicAdd into s.
// ---------------------------------------------------------------------------
__global__ __launch_bounds__(256) void k_expsum(
    const int* __restrict__ ei, float* __restrict__ palpha,
    const float* __restrict__ m, float* __restrict__ s)
{
    const int tid = blockIdx.x * 256 + threadIdx.x;
    const int e = tid >> 2;
    const int b = tid & 3;
    const int dst = ei[E_ + e];
    float4 al = *(const float4*)&palpha[(size_t)tid * 4];
    float4 mm = *(const float4*)&m[((size_t)b * N_ + dst) * 4];
    float4 p;
    p.x = __expf(al.x - mm.x);
    p.y = __expf(al.y - mm.y);
    p.z = __expf(al.z - mm.z);
    p.w = __expf(al.w - mm.w);
    *(float4*)&palpha[(size_t)tid * 4] = p;
    float* sp = &s[((size_t)b * N_ + dst) * 4];
    atomicAdd(&sp[0], p.x);
    atomicAdd(&sp[1], p.y);
    atomicAdd(&sp[2], p.z);
    atomicAdd(&sp[3], p.w);
}

// ---------------------------------------------------------------------------
// Kernel C: one wave per (e,b). lane = o. acc = sum_h w[h]*h[b,src,h,o];
//           atomicAdd(out[b,dst,o], acc/H). Block = 1 edge x 4 batches.
// ---------------------------------------------------------------------------
__global__ __launch_bounds__(256) void k_scatter(
    const int* __restrict__ ei, const float* __restrict__ palpha,
    const float* __restrict__ s, const float* __restrict__ hb,
    float* __restrict__ out)
{
    const int wave = (blockIdx.x * 256 + threadIdx.x) >> 6;  // = e*B + b
    const int lane = threadIdx.x & 63;
    const int e = wave >> 2;
    const int b = wave & 3;
    const int src = ei[e];
    const int dst = ei[E_ + e];
    const float* pp = &palpha[(size_t)wave * 4];
    const float* sp = &s[((size_t)b * N_ + dst) * 4];
    const float* hrow = &hb[((size_t)b * N_ + src) * (H_ * O_)];
    float acc = 0.f;
#pragma unroll
    for (int h = 0; h < H_; ++h) {
        float w = pp[h] / fmaxf(sp[h], 1e-16f);
        acc = fmaf(w, hrow[h * 64 + lane], acc);
    }
    atomicAdd(&out[((size_t)b * N_ + dst) * O_ + lane], 0.25f * acc);
}

// ---------------------------------------------------------------------------
extern "C" void kernel_launch(void* const* d_in, const int* in_sizes, int n_in,
                              void* d_out, int out_size, void* d_ws, size_t ws_size,
                              hipStream_t stream)
{
    (void)in_sizes; (void)n_in; (void)out_size; (void)ws_size;
    const float* x        = (const float*)d_in[0];
    const int*   ei       = (const int*)d_in[1];     // int64 in ref -> int32 here
    const float* eattr    = (const float*)d_in[2];
    const float* Wsrc     = (const float*)d_in[3];
    const float* att_src  = (const float*)d_in[4];
    const float* att_dst  = (const float*)d_in[5];
    const float* W_edge   = (const float*)d_in[6];
    const float* att_edge = (const float*)d_in[7];
    const float* bias     = (const float*)d_in[8];
    float* out = (float*)d_out;

    float* ws     = (float*)d_ws;
    float* hb     = ws;                                  // B*N*H*O = 10,240,000
    float* asrc   = hb   + (size_t)B_ * N_ * H_ * O_;    // B*N*H = 160,000
    float* adst   = asrc + (size_t)B_ * N_ * H_;
    float* m      = adst + (size_t)B_ * N_ * H_;
    float* s      = m    + (size_t)B_ * N_ * H_;
    float* palpha = s    + (size_t)B_ * N_ * H_;         // E*B*H = 2,560,000
    float* c      = palpha + (size_t)E_ * B_ * H_;       // 4

    // init (out<-bias, m<- -inf, s<-0, c)
    hipLaunchKernelGGL(k_init, dim3(4096), dim3(256), 0, stream,
                       out, bias, m, s, W_edge, att_edge, c);
    // projection + attention scalars
    hipLaunchKernelGGL(k_gemm, dim3(B_ * N_ / NODES_PER_BLOCK), dim3(256), 0, stream,
                       x, Wsrc, att_src, att_dst, hb, asrc, adst);
    // edge logits + segment max
    hipLaunchKernelGGL(k_logits, dim3(E_ * B_ / 256), dim3(256), 0, stream,
                       ei, eattr, asrc, adst, c, palpha, m);
    // exp + segment sum
    hipLaunchKernelGGL(k_expsum, dim3(E_ * B_ / 256), dim3(256), 0, stream,
                       ei, palpha, m, s);
    // weighted message scatter (one wave per (e,b))
    hipLaunchKernelGGL(k_scatter, dim3(E_ * B_ / 4), dim3(256), 0, stream,
                       ei, palpha, s, hb, out);
}

// Round 3
// 430.257 us; speedup vs baseline: 1.6297x; 1.6297x over previous
//
#include <hip/hip_runtime.h>
#include <hip/hip_bf16.h>
#include <math.h>

// Problem constants (fixed shapes from the reference)
constexpr int B_  = 4;
constexpr int N_  = 10000;
constexpr int E_  = 160000;
constexpr int D_  = 128;
constexpr int H_  = 4;
constexpr int O_  = 64;
constexpr float NEG_SLOPE = 0.2f;

constexpr int NODES_PER_BLOCK = 16;   // 10000 % 16 == 0 -> 625 blocks per batch

// ---------------------------------------------------------------------------
// Kernel 1: h[b,n,h,o] = sum_d x[b,n,d] * W_src[d,h,o]
//           a_src[b,n,h] = sum_o h * att_src[h,o];  a_dst likewise.
// One block = 16 nodes of one batch. t in [0,256) -> (head = t>>6, o = t&63).
// ---------------------------------------------------------------------------
__global__ __launch_bounds__(256) void k_gemm(
    const float* __restrict__ x, const float* __restrict__ Wsrc,
    const float* __restrict__ att_src, const float* __restrict__ att_dst,
    float* __restrict__ hb, float* __restrict__ asrc, float* __restrict__ adst)
{
    __shared__ float xs[NODES_PER_BLOCK][D_];
    const int t = threadIdx.x;
    const int head = t >> 6, o = t & 63;
    const int blocks_per_batch = N_ / NODES_PER_BLOCK;   // 625
    const int b  = blockIdx.x / blocks_per_batch;
    const int n0 = (blockIdx.x % blocks_per_batch) * NODES_PER_BLOCK;

    const float* xrow = x + ((size_t)b * N_ + n0) * D_;  // 16*128 contiguous floats
    for (int i = t; i < NODES_PER_BLOCK * D_; i += 256)
        ((float*)xs)[i] = xrow[i];
    __syncthreads();

    float acc[NODES_PER_BLOCK];
#pragma unroll
    for (int i = 0; i < NODES_PER_BLOCK; ++i) acc[i] = 0.f;

    for (int d = 0; d < D_; d += 4) {
        float w0 = Wsrc[(size_t)(d + 0) * 256 + t];
        float w1 = Wsrc[(size_t)(d + 1) * 256 + t];
        float w2 = Wsrc[(size_t)(d + 2) * 256 + t];
        float w3 = Wsrc[(size_t)(d + 3) * 256 + t];
#pragma unroll
        for (int i = 0; i < NODES_PER_BLOCK; ++i) {
            float4 xv = *(const float4*)&xs[i][d];
            acc[i] = fmaf(xv.x, w0, acc[i]);
            acc[i] = fmaf(xv.y, w1, acc[i]);
            acc[i] = fmaf(xv.z, w2, acc[i]);
            acc[i] = fmaf(xv.w, w3, acc[i]);
        }
    }

    const float as_w = att_src[t];
    const float ad_w = att_dst[t];
#pragma unroll
    for (int i = 0; i < NODES_PER_BLOCK; ++i) {
        const int n = n0 + i;
        hb[(((size_t)b * N_ + n) * H_ + head) * O_ + o] = acc[i];
        float v1 = acc[i] * as_w;
        float v2 = acc[i] * ad_w;
#pragma unroll
        for (int off = 32; off > 0; off >>= 1) {
            v1 += __shfl_down(v1, off, 64);
            v2 += __shfl_down(v2, off, 64);
        }
        if (o == 0) {
            asrc[((size_t)b * N_ + n) * H_ + head] = v1;
            adst[((size_t)b * N_ + n) * H_ + head] = v2;
        }
    }
}

// ---------------------------------------------------------------------------
// Init: out <- bias broadcast, s <- 0, c[h] = sum_o We[h,o]*ae[h,o]
// ---------------------------------------------------------------------------
__global__ void k_init(float* __restrict__ out, const float* __restrict__ bias,
                       float* __restrict__ s,
                       const float* __restrict__ W_edge,
                       const float* __restrict__ att_edge,
                       float* __restrict__ c)
{
    const int stride = gridDim.x * blockDim.x;
    const int idx = blockIdx.x * blockDim.x + threadIdx.x;
    const int total_out = B_ * N_ * O_;   // 2,560,000
    const int total_s   = B_ * N_ * H_;   // 160,000
    for (int i = idx; i < total_out; i += stride) out[i] = bias[i & 63];
    for (int i = idx; i < total_s; i += stride) s[i] = 0.f;
    if (blockIdx.x == 0) {
        float v = W_edge[threadIdx.x] * att_edge[threadIdx.x];
#pragma unroll
        for (int off = 32; off > 0; off >>= 1) v += __shfl_down(v, off, 64);
        if ((threadIdx.x & 63) == 0) c[threadIdx.x >> 6] = v;
    }
}

// ---------------------------------------------------------------------------
// Fused edge kernel: per (e,b):
//   p = exp(leaky_relu(a_src[src]+a_dst[dst]+ea*c))   (softmax shift-invariance
//   makes the segment-max subtraction a mathematical no-op -> skip it)
//   store p; atomicAdd into s[dst,b,h]  (native f32 atomics only).
// ---------------------------------------------------------------------------
__global__ __launch_bounds__(256) void k_edge(
    const int* __restrict__ ei, const float* __restrict__ eattr,
    const float* __restrict__ asrc, const float* __restrict__ adst,
    const float* __restrict__ c, float* __restrict__ palpha, float* __restrict__ s)
{
    const int tid = blockIdx.x * 256 + threadIdx.x;   // tid = e*B + b
    const int e = tid >> 2;
    const int b = tid & 3;
    const int src = ei[e];
    const int dst = ei[E_ + e];
    const float ea = eattr[e];
    float4 as = *(const float4*)&asrc[((size_t)b * N_ + src) * 4];
    float4 ad = *(const float4*)&adst[((size_t)b * N_ + dst) * 4];
    float4 cc = *(const float4*)c;
    float4 al;
    al.x = as.x + ad.x + ea * cc.x;
    al.y = as.y + ad.y + ea * cc.y;
    al.z = as.z + ad.z + ea * cc.z;
    al.w = as.w + ad.w + ea * cc.w;
    al.x = al.x > 0.f ? al.x : NEG_SLOPE * al.x;
    al.y = al.y > 0.f ? al.y : NEG_SLOPE * al.y;
    al.z = al.z > 0.f ? al.z : NEG_SLOPE * al.z;
    al.w = al.w > 0.f ? al.w : NEG_SLOPE * al.w;
    float4 p;
    p.x = __expf(al.x);
    p.y = __expf(al.y);
    p.z = __expf(al.z);
    p.w = __expf(al.w);
    *(float4*)&palpha[(size_t)tid * 4] = p;
    float* sp = &s[((size_t)b * N_ + dst) * 4];
    atomicAdd(&sp[0], p.x);
    atomicAdd(&sp[1], p.y);
    atomicAdd(&sp[2], p.z);
    atomicAdd(&sp[3], p.w);
}

// ---------------------------------------------------------------------------
// Kernel C: one wave per (e,b). lane = o. acc = sum_h w[h]*h[b,src,h,o];
//           atomicAdd(out[b,dst,o], acc/H). Block = 1 edge x 4 batches.
// ---------------------------------------------------------------------------
__global__ __launch_bounds__(256) void k_scatter(
    const int* __restrict__ ei, const float* __restrict__ palpha,
    const float* __restrict__ s, const float* __restrict__ hb,
    float* __restrict__ out)
{
    const int wave = (blockIdx.x * 256 + threadIdx.x) >> 6;  // = e*B + b
    const int lane = threadIdx.x & 63;
    const int e = wave >> 2;
    const int b = wave & 3;
    const int src = ei[e];
    const int dst = ei[E_ + e];
    const float* pp = &palpha[(size_t)wave * 4];
    const float* sp = &s[((size_t)b * N_ + dst) * 4];
    const float* hrow = &hb[((size_t)b * N_ + src) * (H_ * O_)];
    float acc = 0.f;
#pragma unroll
    for (int h = 0; h < H_; ++h) {
        float w = pp[h] / fmaxf(sp[h], 1e-16f);
        acc = fmaf(w, hrow[h * 64 + lane], acc);
    }
    atomicAdd(&out[((size_t)b * N_ + dst) * O_ + lane], 0.25f * acc);
}

// ---------------------------------------------------------------------------
extern "C" void kernel_launch(void* const* d_in, const int* in_sizes, int n_in,
                              void* d_out, int out_size, void* d_ws, size_t ws_size,
                              hipStream_t stream)
{
    (void)in_sizes; (void)n_in; (void)out_size; (void)ws_size;
    const float* x        = (const float*)d_in[0];
    const int*   ei       = (const int*)d_in[1];     // int64 in ref -> int32 here
    const float* eattr    = (const float*)d_in[2];
    const float* Wsrc     = (const float*)d_in[3];
    const float* att_src  = (const float*)d_in[4];
    const float* att_dst  = (const float*)d_in[5];
    const float* W_edge   = (const float*)d_in[6];
    const float* att_edge = (const float*)d_in[7];
    const float* bias     = (const float*)d_in[8];
    float* out = (float*)d_out;

    float* ws     = (float*)d_ws;
    float* hb     = ws;                                  // B*N*H*O = 10,240,000
    float* asrc   = hb   + (size_t)B_ * N_ * H_ * O_;    // B*N*H = 160,000
    float* adst   = asrc + (size_t)B_ * N_ * H_;
    float* s      = adst + (size_t)B_ * N_ * H_;
    float* palpha = s    + (size_t)B_ * N_ * H_;         // E*B*H = 2,560,000
    float* c      = palpha + (size_t)E_ * B_ * H_;       // 4

    // init (out<-bias, s<-0, c)
    hipLaunchKernelGGL(k_init, dim3(4096), dim3(256), 0, stream,
                       out, bias, s, W_edge, att_edge, c);
    // projection + attention scalars
    hipLaunchKernelGGL(k_gemm, dim3(B_ * N_ / NODES_PER_BLOCK), dim3(256), 0, stream,
                       x, Wsrc, att_src, att_dst, hb, asrc, adst);
    // fused edge logits + exp + segment sum (no segment max needed)
    hipLaunchKernelGGL(k_edge, dim3(E_ * B_ / 256), dim3(256), 0, stream,
                       ei, eattr, asrc, adst, c, palpha, s);
    // weighted message scatter (one wave per (e,b))
    hipLaunchKernelGGL(k_scatter, dim3(E_ * B_ / 4), dim3(256), 0, stream,
                       ei, palpha, s, hb, out);
}

// Round 4
// 272.173 us; speedup vs baseline: 2.5762x; 1.5808x over previous
//
#include <hip/hip_runtime.h>
#include <hip/hip_bf16.h>
#include <math.h>

// Problem constants (fixed shapes from the reference)
constexpr int B_  = 4;
constexpr int N_  = 10000;
constexpr int E_  = 160000;
constexpr int D_  = 128;
constexpr int H_  = 4;
constexpr int O_  = 64;
constexpr float NEG_SLOPE = 0.2f;

constexpr int NODES_PER_BLOCK = 16;   // k_gemm: 10000 % 16 == 0 -> 625 blocks/batch

// ---------------------------------------------------------------------------
// k_gemm: h[b,n,:,:] = x[b,n,:] @ W_src; stored as bf16 in [b][n][o][h] layout
//         (lane reads all 4 heads of one o as a single 8B ushort4 in k_agg).
//         a_src[b,n,h] / a_dst[b,n,h] via wave reduction.
// ---------------------------------------------------------------------------
__global__ __launch_bounds__(256) void k_gemm(
    const float* __restrict__ x, const float* __restrict__ Wsrc,
    const float* __restrict__ att_src, const float* __restrict__ att_dst,
    __hip_bfloat16* __restrict__ hb, float* __restrict__ asrc, float* __restrict__ adst)
{
    __shared__ float xs[NODES_PER_BLOCK][D_];
    const int t = threadIdx.x;
    const int head = t >> 6, o = t & 63;
    const int blocks_per_batch = N_ / NODES_PER_BLOCK;   // 625
    const int b  = blockIdx.x / blocks_per_batch;
    const int n0 = (blockIdx.x % blocks_per_batch) * NODES_PER_BLOCK;

    const float* xrow = x + ((size_t)b * N_ + n0) * D_;
    for (int i = t; i < NODES_PER_BLOCK * D_; i += 256)
        ((float*)xs)[i] = xrow[i];
    __syncthreads();

    float acc[NODES_PER_BLOCK];
#pragma unroll
    for (int i = 0; i < NODES_PER_BLOCK; ++i) acc[i] = 0.f;

    for (int d = 0; d < D_; d += 4) {
        float w0 = Wsrc[(size_t)(d + 0) * 256 + t];
        float w1 = Wsrc[(size_t)(d + 1) * 256 + t];
        float w2 = Wsrc[(size_t)(d + 2) * 256 + t];
        float w3 = Wsrc[(size_t)(d + 3) * 256 + t];
#pragma unroll
        for (int i = 0; i < NODES_PER_BLOCK; ++i) {
            float4 xv = *(const float4*)&xs[i][d];
            acc[i] = fmaf(xv.x, w0, acc[i]);
            acc[i] = fmaf(xv.y, w1, acc[i]);
            acc[i] = fmaf(xv.z, w2, acc[i]);
            acc[i] = fmaf(xv.w, w3, acc[i]);
        }
    }

    const float as_w = att_src[t];
    const float ad_w = att_dst[t];
#pragma unroll
    for (int i = 0; i < NODES_PER_BLOCK; ++i) {
        const int n = n0 + i;
        // transposed bf16 store: [b][n][o][h]
        hb[(((size_t)b * N_ + n) * O_ + o) * H_ + head] = __float2bfloat16(acc[i]);
        float v1 = acc[i] * as_w;
        float v2 = acc[i] * ad_w;
#pragma unroll
        for (int off = 32; off > 0; off >>= 1) {
            v1 += __shfl_down(v1, off, 64);
            v2 += __shfl_down(v2, off, 64);
        }
        if (o == 0) {
            asrc[((size_t)b * N_ + n) * H_ + head] = v1;
            adst[((size_t)b * N_ + n) * H_ + head] = v2;
        }
    }
}

// ---------------------------------------------------------------------------
// k_init: zero deg[], compute c[h] = sum_o W_edge[h,o]*att_edge[h,o]
// ---------------------------------------------------------------------------
__global__ void k_init(int* __restrict__ deg,
                       const float* __restrict__ W_edge,
                       const float* __restrict__ att_edge,
                       float* __restrict__ c)
{
    const int idx = blockIdx.x * blockDim.x + threadIdx.x;
    const int stride = gridDim.x * blockDim.x;
    for (int i = idx; i < N_; i += stride) deg[i] = 0;
    if (blockIdx.x == 0 && threadIdx.x < 256) {
        float v = W_edge[threadIdx.x] * att_edge[threadIdx.x];
#pragma unroll
        for (int off = 32; off > 0; off >>= 1) v += __shfl_down(v, off, 64);
        if ((threadIdx.x & 63) == 0) c[threadIdx.x >> 6] = v;
    }
}

// ---------------------------------------------------------------------------
// k_hist: deg[dst]++ per edge
// ---------------------------------------------------------------------------
__global__ __launch_bounds__(256) void k_hist(const int* __restrict__ ei,
                                              int* __restrict__ deg)
{
    const int e = blockIdx.x * 256 + threadIdx.x;
    if (e < E_) atomicAdd(&deg[ei[E_ + e]], 1);
}

// ---------------------------------------------------------------------------
// k_scan: single-block exclusive prefix sum over deg[N] -> rowptr[N+1], cursor
// ---------------------------------------------------------------------------
__global__ __launch_bounds__(1024) void k_scan(const int* __restrict__ deg,
                                               int* __restrict__ rowptr,
                                               int* __restrict__ cursor)
{
    __shared__ int sm[1024];
    const int t = threadIdx.x;
    int carry = 0;
    for (int c0 = 0; c0 < N_; c0 += 1024) {
        const int i = c0 + t;
        const int v = (i < N_) ? deg[i] : 0;
        sm[t] = v;
        __syncthreads();
        for (int off = 1; off < 1024; off <<= 1) {
            int add = (t >= off) ? sm[t - off] : 0;
            __syncthreads();
            sm[t] += add;
            __syncthreads();
        }
        const int incl = sm[t];
        if (i < N_) { rowptr[i] = carry + incl - v; cursor[i] = carry + incl - v; }
        const int tot = sm[1023];
        __syncthreads();
        carry += tot;
    }
    if (t == 0) rowptr[N_] = carry;
}

// ---------------------------------------------------------------------------
// k_place: counting-sort edges by dst into (srcSorted, dstSorted, eaSorted)
// ---------------------------------------------------------------------------
__global__ __launch_bounds__(256) void k_place(
    const int* __restrict__ ei, const float* __restrict__ eattr,
    int* __restrict__ cursor, int* __restrict__ srcSorted,
    int* __restrict__ dstSorted, float* __restrict__ eaSorted)
{
    const int e = blockIdx.x * 256 + threadIdx.x;
    if (e >= E_) return;
    const int dst = ei[E_ + e];
    const int pos = atomicAdd(&cursor[dst], 1);
    srcSorted[pos] = ei[e];
    dstSorted[pos] = dst;
    eaSorted[pos]  = eattr[e];
}

// ---------------------------------------------------------------------------
// k_edge: per (pos,b): p = exp(leaky(a_src[src]+a_dst[dst]+ea*c)); coalesced
//         store to psorted[pos][b][4]. (softmax shift-invariance: no max.)
// ---------------------------------------------------------------------------
__global__ __launch_bounds__(256) void k_edge(
    const int* __restrict__ srcSorted, const int* __restrict__ dstSorted,
    const float* __restrict__ eaSorted,
    const float* __restrict__ asrc, const float* __restrict__ adst,
    const float* __restrict__ c, float* __restrict__ psorted)
{
    const int tid = blockIdx.x * 256 + threadIdx.x;   // tid = pos*B + b
    const int pos = tid >> 2;
    const int b   = tid & 3;
    const int src = srcSorted[pos];
    const int dst = dstSorted[pos];
    const float ea = eaSorted[pos];
    float4 as = *(const float4*)&asrc[((size_t)b * N_ + src) * 4];
    float4 ad = *(const float4*)&adst[((size_t)b * N_ + dst) * 4];
    float4 cc = *(const float4*)c;
    float4 al;
    al.x = as.x + ad.x + ea * cc.x;
    al.y = as.y + ad.y + ea * cc.y;
    al.z = as.z + ad.z + ea * cc.z;
    al.w = as.w + ad.w + ea * cc.w;
    al.x = al.x > 0.f ? al.x : NEG_SLOPE * al.x;
    al.y = al.y > 0.f ? al.y : NEG_SLOPE * al.y;
    al.z = al.z > 0.f ? al.z : NEG_SLOPE * al.z;
    al.w = al.w > 0.f ? al.w : NEG_SLOPE * al.w;
    float4 p;
    p.x = __expf(al.x);
    p.y = __expf(al.y);
    p.z = __expf(al.z);
    p.w = __expf(al.w);
    *(float4*)&psorted[(size_t)tid * 4] = p;
}

// ---------------------------------------------------------------------------
// k_agg: one wave per (dst,b). Iterate CSR in-edges; accumulate per-head
//        weighted sums AND the softmax denominator in registers; single
//        non-atomic out write. b = blockIdx&3 -> per-XCD batch affinity.
// ---------------------------------------------------------------------------
__global__ __launch_bounds__(256) void k_agg(
    const int* __restrict__ rowptr, const int* __restrict__ srcSorted,
    const float* __restrict__ psorted, const unsigned short* __restrict__ hbu,
    const float* __restrict__ bias, float* __restrict__ out)
{
    const int b    = blockIdx.x & 3;
    const int g    = blockIdx.x >> 2;
    const int wave = threadIdx.x >> 6;
    const int lane = threadIdx.x & 63;
    const int dst  = g * 4 + wave;

    const int start = rowptr[dst];
    const int end   = rowptr[dst + 1];

    float a0 = 0.f, a1 = 0.f, a2 = 0.f, a3 = 0.f;
    float s0 = 0.f, s1 = 0.f, s2 = 0.f, s3 = 0.f;

    for (int j = start; j < end; ++j) {
        float4 p = *(const float4*)&psorted[((size_t)j * 4 + b) * 4];  // uniform
        int src = srcSorted[j];                                        // uniform
        s0 += p.x; s1 += p.y; s2 += p.z; s3 += p.w;
        ushort4 hv = *(const ushort4*)&hbu[(((size_t)b * N_ + src) * O_ + lane) * H_];
        float f0 = __uint_as_float((unsigned)hv.x << 16);
        float f1 = __uint_as_float((unsigned)hv.y << 16);
        float f2 = __uint_as_float((unsigned)hv.z << 16);
        float f3 = __uint_as_float((unsigned)hv.w << 16);
        a0 = fmaf(p.x, f0, a0);
        a1 = fmaf(p.y, f1, a1);
        a2 = fmaf(p.z, f2, a2);
        a3 = fmaf(p.w, f3, a3);
    }

    float r = a0 / fmaxf(s0, 1e-16f) + a1 / fmaxf(s1, 1e-16f)
            + a2 / fmaxf(s2, 1e-16f) + a3 / fmaxf(s3, 1e-16f);
    out[((size_t)b * N_ + dst) * O_ + lane] = 0.25f * r + bias[lane];
}

// ---------------------------------------------------------------------------
extern "C" void kernel_launch(void* const* d_in, const int* in_sizes, int n_in,
                              void* d_out, int out_size, void* d_ws, size_t ws_size,
                              hipStream_t stream)
{
    (void)in_sizes; (void)n_in; (void)out_size; (void)ws_size;
    const float* x        = (const float*)d_in[0];
    const int*   ei       = (const int*)d_in[1];     // int64 in ref -> int32 here
    const float* eattr    = (const float*)d_in[2];
    const float* Wsrc     = (const float*)d_in[3];
    const float* att_src  = (const float*)d_in[4];
    const float* att_dst  = (const float*)d_in[5];
    const float* W_edge   = (const float*)d_in[6];
    const float* att_edge = (const float*)d_in[7];
    const float* bias     = (const float*)d_in[8];
    float* out = (float*)d_out;

    // workspace carve-up (16B-aligned chunks)
    char* w = (char*)d_ws;
    auto take = [&](size_t bytes) { char* p = w; w += (bytes + 15) & ~size_t(15); return p; };
    __hip_bfloat16* hb    = (__hip_bfloat16*)take((size_t)B_ * N_ * O_ * H_ * 2); // 20.48 MB
    float* asrc    = (float*)take((size_t)B_ * N_ * H_ * 4);                      // 640 KB
    float* adst    = (float*)take((size_t)B_ * N_ * H_ * 4);
    float* psorted = (float*)take((size_t)E_ * B_ * H_ * 4);                      // 10.24 MB
    float* c       = (float*)take(4 * 4);
    int* deg       = (int*)take((size_t)N_ * 4);
    int* rowptr    = (int*)take((size_t)(N_ + 1) * 4);
    int* cursor    = (int*)take((size_t)N_ * 4);
    int* srcSorted = (int*)take((size_t)E_ * 4);
    int* dstSorted = (int*)take((size_t)E_ * 4);
    float* eaSorted= (float*)take((size_t)E_ * 4);

    hipLaunchKernelGGL(k_init, dim3(40), dim3(256), 0, stream,
                       deg, W_edge, att_edge, c);
    hipLaunchKernelGGL(k_gemm, dim3(B_ * N_ / NODES_PER_BLOCK), dim3(256), 0, stream,
                       x, Wsrc, att_src, att_dst, hb, asrc, adst);
    hipLaunchKernelGGL(k_hist, dim3((E_ + 255) / 256), dim3(256), 0, stream, ei, deg);
    hipLaunchKernelGGL(k_scan, dim3(1), dim3(1024), 0, stream, deg, rowptr, cursor);
    hipLaunchKernelGGL(k_place, dim3((E_ + 255) / 256), dim3(256), 0, stream,
                       ei, eattr, cursor, srcSorted, dstSorted, eaSorted);
    hipLaunchKernelGGL(k_edge, dim3(E_ * B_ / 256), dim3(256), 0, stream,
                       srcSorted, dstSorted, eaSorted, asrc, adst, c, psorted);
    hipLaunchKernelGGL(k_agg, dim3(N_ / 4 * B_), dim3(256), 0, stream,
                       rowptr, srcSorted, psorted, (const unsigned short*)hb, bias, out);
}

// Round 5
// 250.578 us; speedup vs baseline: 2.7983x; 1.0862x over previous
//
#include <hip/hip_runtime.h>
#include <hip/hip_bf16.h>
#include <math.h>

// Problem constants (fixed shapes from the reference)
constexpr int B_  = 4;
constexpr int N_  = 10000;
constexpr int E_  = 160000;
constexpr int D_  = 128;
constexpr int H_  = 4;
constexpr int O_  = 64;
constexpr float NEG_SLOPE = 0.2f;

using short8 = __attribute__((ext_vector_type(8))) short;
using f32x4  = __attribute__((ext_vector_type(4))) float;

static __device__ __forceinline__ unsigned short f2bf(float f) {
    unsigned u = __float_as_uint(f);
    u += 0x7fffu + ((u >> 16) & 1u);           // RN-even
    return (unsigned short)(u >> 16);
}
static __device__ __forceinline__ float bf2f(unsigned short h) {
    return __uint_as_float((unsigned)h << 16);
}

// ---------------------------------------------------------------------------
// k_init: zero deg[], compute c[h] = sum_o W_edge[h,o]*att_edge[h,o]
// ---------------------------------------------------------------------------
__global__ void k_init(int* __restrict__ deg,
                       const float* __restrict__ W_edge,
                       const float* __restrict__ att_edge,
                       float* __restrict__ c)
{
    const int idx = blockIdx.x * blockDim.x + threadIdx.x;
    const int stride = gridDim.x * blockDim.x;
    for (int i = idx; i < N_; i += stride) deg[i] = 0;
    if (blockIdx.x == 0 && threadIdx.x < 256) {
        float v = W_edge[threadIdx.x] * att_edge[threadIdx.x];
#pragma unroll
        for (int off = 32; off > 0; off >>= 1) v += __shfl_down(v, off, 64);
        if ((threadIdx.x & 63) == 0) c[threadIdx.x >> 6] = v;
    }
}

// ---------------------------------------------------------------------------
// k_wprep: per d (block), per t=h*64+o (thread):
//   W1t[c][d], W2t[c][d] bf16 split of Wsrc[d][h][o], c = o*4+h  (B-operand,
//   [col][k] so MFMA B-fragments are 16B-contiguous)
//   v_src[d][h] = sum_o Wsrc[d][h][o]*att_src[h][o]; v_dst likewise.
// ---------------------------------------------------------------------------
__global__ __launch_bounds__(256) void k_wprep(
    const float* __restrict__ Wsrc, const float* __restrict__ att_src,
    const float* __restrict__ att_dst,
    unsigned short* __restrict__ W1t, unsigned short* __restrict__ W2t,
    float* __restrict__ vsrc, float* __restrict__ vdst)
{
    const int d = blockIdx.x;
    const int t = threadIdx.x;
    const int h = t >> 6;
    const float wv = Wsrc[(size_t)d * 256 + t];
    const unsigned short w1 = f2bf(wv);
    const unsigned short w2 = f2bf(wv - bf2f(w1));
    const int c = ((t & 63) << 2) | h;       // o*4 + head
    W1t[(size_t)c * 128 + d] = w1;
    W2t[(size_t)c * 128 + d] = w2;

    float vs = wv * att_src[t];
    float vd = wv * att_dst[t];
#pragma unroll
    for (int off = 32; off > 0; off >>= 1) {
        vs += __shfl_down(vs, off, 64);
        vd += __shfl_down(vd, off, 64);
    }
    if ((t & 63) == 0) {
        vsrc[d * 4 + h] = vs;
        vdst[d * 4 + h] = vd;
    }
}

// ---------------------------------------------------------------------------
// k_gemm (MFMA): rows = flat b*N+n (40000), cols c = o*4+head (256), K = 128.
// Split-precision: h = x1@W1 + x1@W2 + x2@W1 (fp32-accurate), stored bf16 to
// hb[row][c]. Epilogue also computes exact a_src/a_dst = x . v_{src,dst}.
// Block: 64 rows, 4 waves; wave w owns rows 16w..16w+15, all 256 cols.
// ---------------------------------------------------------------------------
__global__ __launch_bounds__(256) void k_gemm(
    const float* __restrict__ x,
    const unsigned short* __restrict__ W1t, const unsigned short* __restrict__ W2t,
    const float* __restrict__ vsrc, const float* __restrict__ vdst,
    unsigned short* __restrict__ hbw, float* __restrict__ asrc, float* __restrict__ adst)
{
    constexpr int APAD = 136;                // ushort stride (128+8): conflict-safe
    __shared__ unsigned short A1[64 * APAD];
    __shared__ unsigned short A2[64 * APAD];
    __shared__ float4 vsL[128];
    __shared__ float4 vdL[128];

    const int t = threadIdx.x;
    const int w = t >> 6;                    // wave 0..3
    const int lane = t & 63;
    const int i = lane & 15;                 // col-in-tile / row-in-frag
    const int q = lane >> 4;                 // quad 0..3
    const size_t rowbase = (size_t)blockIdx.x * 64;

    // ---- stage x -> bf16 hi/lo in LDS (+ v vectors) ----
    {
        const float4* xg = (const float4*)(x + rowbase * D_);
#pragma unroll
        for (int it = 0; it < 8; ++it) {
            const int idx = it * 256 + t;    // 2048 float4 = 64 rows x 32
            const int row = idx >> 5;
            const int c4  = idx & 31;
            float4 xv = xg[idx];
            ushort4 h1, h2;
            h1.x = f2bf(xv.x); h2.x = f2bf(xv.x - bf2f(h1.x));
            h1.y = f2bf(xv.y); h2.y = f2bf(xv.y - bf2f(h1.y));
            h1.z = f2bf(xv.z); h2.z = f2bf(xv.z - bf2f(h1.z));
            h1.w = f2bf(xv.w); h2.w = f2bf(xv.w - bf2f(h1.w));
            *(ushort4*)&A1[row * APAD + c4 * 4] = h1;
            *(ushort4*)&A2[row * APAD + c4 * 4] = h2;
        }
        if (t < 128) vsL[t] = ((const float4*)vsrc)[t];
        else         vdL[t - 128] = ((const float4*)vdst)[t - 128];
    }
    __syncthreads();

    // ---- MFMA main loop ----
    f32x4 acc[16];
#pragma unroll
    for (int ct = 0; ct < 16; ++ct) acc[ct] = (f32x4){0.f, 0.f, 0.f, 0.f};

#pragma unroll
    for (int ks = 0; ks < 4; ++ks) {
        const int aoff = (w * 16 + i) * APAD + ks * 32 + q * 8;
        short8 a1 = *(const short8*)&A1[aoff];
        short8 a2 = *(const short8*)&A2[aoff];
#pragma unroll
        for (int ct = 0; ct < 16; ++ct) {
            const size_t boff = (size_t)(ct * 16 + i) * 128 + ks * 32 + q * 8;
            short8 b1 = *(const short8*)&W1t[boff];
            short8 b2 = *(const short8*)&W2t[boff];
            acc[ct] = __builtin_amdgcn_mfma_f32_16x16x32_bf16(a1, b1, acc[ct], 0, 0, 0);
            acc[ct] = __builtin_amdgcn_mfma_f32_16x16x32_bf16(a2, b1, acc[ct], 0, 0, 0);
            acc[ct] = __builtin_amdgcn_mfma_f32_16x16x32_bf16(a1, b2, acc[ct], 0, 0, 0);
        }
    }

    // ---- epilogue 1: exact a_src/a_dst from (A1+A2) . v ----
    {
        const int row_l = w * 16 + i;        // lane's att row
        float s0 = 0, s1 = 0, s2 = 0, s3 = 0, d0 = 0, d1 = 0, d2 = 0, d3 = 0;
#pragma unroll 8
        for (int dd = 0; dd < 32; ++dd) {
            const int d = q * 32 + dd;
            const float xv = bf2f(A1[row_l * APAD + d]) + bf2f(A2[row_l * APAD + d]);
            float4 vs = vsL[d], vd = vdL[d];
            s0 = fmaf(xv, vs.x, s0); s1 = fmaf(xv, vs.y, s1);
            s2 = fmaf(xv, vs.z, s2); s3 = fmaf(xv, vs.w, s3);
            d0 = fmaf(xv, vd.x, d0); d1 = fmaf(xv, vd.y, d1);
            d2 = fmaf(xv, vd.z, d2); d3 = fmaf(xv, vd.w, d3);
        }
#pragma unroll
        for (int off = 32; off >= 16; off >>= 1) {
            s0 += __shfl_down(s0, off, 64); s1 += __shfl_down(s1, off, 64);
            s2 += __shfl_down(s2, off, 64); s3 += __shfl_down(s3, off, 64);
            d0 += __shfl_down(d0, off, 64); d1 += __shfl_down(d1, off, 64);
            d2 += __shfl_down(d2, off, 64); d3 += __shfl_down(d3, off, 64);
        }
        if (q == 0) {
            const size_t rg = rowbase + row_l;
            *(float4*)&asrc[rg * 4] = make_float4(s0, s1, s2, s3);
            *(float4*)&adst[rg * 4] = make_float4(d0, d1, d2, d3);
        }
    }

    // ---- epilogue 2: store hb bf16. C/D layout: col=lane&15, row=q*4+reg ----
#pragma unroll
    for (int ct = 0; ct < 16; ++ct) {
#pragma unroll
        for (int r = 0; r < 4; ++r) {
            const size_t rg = rowbase + w * 16 + q * 4 + r;
            hbw[rg * 256 + ct * 16 + i] = f2bf(acc[ct][r]);
        }
    }
}

// ---------------------------------------------------------------------------
// k_hist: deg[dst]++ per edge
// ---------------------------------------------------------------------------
__global__ __launch_bounds__(256) void k_hist(const int* __restrict__ ei,
                                              int* __restrict__ deg)
{
    const int e = blockIdx.x * 256 + threadIdx.x;
    if (e < E_) atomicAdd(&deg[ei[E_ + e]], 1);
}

// ---------------------------------------------------------------------------
// k_scan: single-block exclusive prefix sum (shfl-based, 2 barriers/chunk)
// ---------------------------------------------------------------------------
__global__ __launch_bounds__(1024) void k_scan(const int* __restrict__ deg,
                                               int* __restrict__ rowptr,
                                               int* __restrict__ cursor)
{
    __shared__ int wsum[16];
    __shared__ int wexcl[16];
    __shared__ int btot;
    const int t = threadIdx.x, wv = t >> 6, ln = t & 63;
    int carry = 0;
    for (int c0 = 0; c0 < N_; c0 += 1024) {
        const int idx = c0 + t;
        const int v = (idx < N_) ? deg[idx] : 0;
        int incl = v;
#pragma unroll
        for (int off = 1; off < 64; off <<= 1) {
            int u = __shfl_up(incl, off, 64);
            if (ln >= off) incl += u;
        }
        if (ln == 63) wsum[wv] = incl;
        __syncthreads();
        if (wv == 0) {
            int s = (ln < 16) ? wsum[ln] : 0;
            int si = s;
#pragma unroll
            for (int off = 1; off < 16; off <<= 1) {
                int u = __shfl_up(si, off, 64);
                if (ln >= off) si += u;
            }
            if (ln < 16) wexcl[ln] = si - s;
            if (ln == 15) btot = si;
        }
        __syncthreads();
        const int excl = carry + wexcl[wv] + incl - v;
        if (idx < N_) { rowptr[idx] = excl; cursor[idx] = excl; }
        carry += btot;
        __syncthreads();
    }
    if (t == 0) rowptr[N_] = carry;
}

// ---------------------------------------------------------------------------
// k_place: counting-sort edges by dst
// ---------------------------------------------------------------------------
__global__ __launch_bounds__(256) void k_place(
    const int* __restrict__ ei, const float* __restrict__ eattr,
    int* __restrict__ cursor, int* __restrict__ srcSorted,
    int* __restrict__ dstSorted, float* __restrict__ eaSorted)
{
    const int e = blockIdx.x * 256 + threadIdx.x;
    if (e >= E_) return;
    const int dst = ei[E_ + e];
    const int pos = atomicAdd(&cursor[dst], 1);
    srcSorted[pos] = ei[e];
    dstSorted[pos] = dst;
    eaSorted[pos]  = eattr[e];
}

// ---------------------------------------------------------------------------
// k_edge: per (pos,b): p = exp(leaky(a_src[src]+a_dst[dst]+ea*c))
//         (softmax shift-invariance: no segment max needed)
// ---------------------------------------------------------------------------
__global__ __launch_bounds__(256) void k_edge(
    const int* __restrict__ srcSorted, const int* __restrict__ dstSorted,
    const float* __restrict__ eaSorted,
    const float* __restrict__ asrc, const float* __restrict__ adst,
    const float* __restrict__ c, float* __restrict__ psorted)
{
    const int tid = blockIdx.x * 256 + threadIdx.x;   // tid = pos*B + b
    const int pos = tid >> 2;
    const int b   = tid & 3;
    const int src = srcSorted[pos];
    const int dst = dstSorted[pos];
    const float ea = eaSorted[pos];
    float4 as = *(const float4*)&asrc[((size_t)b * N_ + src) * 4];
    float4 ad = *(const float4*)&adst[((size_t)b * N_ + dst) * 4];
    float4 cc = *(const float4*)c;
    float4 al;
    al.x = as.x + ad.x + ea * cc.x;
    al.y = as.y + ad.y + ea * cc.y;
    al.z = as.z + ad.z + ea * cc.z;
    al.w = as.w + ad.w + ea * cc.w;
    al.x = al.x > 0.f ? al.x : NEG_SLOPE * al.x;
    al.y = al.y > 0.f ? al.y : NEG_SLOPE * al.y;
    al.z = al.z > 0.f ? al.z : NEG_SLOPE * al.z;
    al.w = al.w > 0.f ? al.w : NEG_SLOPE * al.w;
    float4 p;
    p.x = __expf(al.x);
    p.y = __expf(al.y);
    p.z = __expf(al.z);
    p.w = __expf(al.w);
    *(float4*)&psorted[(size_t)tid * 4] = p;
}

// ---------------------------------------------------------------------------
// k_agg: one wave per (dst,b); CSR in-edge gather; register softmax denom;
//        single non-atomic out write.
// ---------------------------------------------------------------------------
__global__ __launch_bounds__(256) void k_agg(
    const int* __restrict__ rowptr, const int* __restrict__ srcSorted,
    const float* __restrict__ psorted, const unsigned short* __restrict__ hbu,
    const float* __restrict__ bias, float* __restrict__ out)
{
    const int b    = blockIdx.x & 3;
    const int g    = blockIdx.x >> 2;
    const int wave = threadIdx.x >> 6;
    const int lane = threadIdx.x & 63;
    const int dst  = g * 4 + wave;

    const int start = rowptr[dst];
    const int end   = rowptr[dst + 1];

    float a0 = 0.f, a1 = 0.f, a2 = 0.f, a3 = 0.f;
    float s0 = 0.f, s1 = 0.f, s2 = 0.f, s3 = 0.f;

    for (int j = start; j < end; ++j) {
        float4 p = *(const float4*)&psorted[((size_t)j * 4 + b) * 4];  // uniform
        int src = srcSorted[j];                                        // uniform
        s0 += p.x; s1 += p.y; s2 += p.z; s3 += p.w;
        ushort4 hv = *(const ushort4*)&hbu[(((size_t)b * N_ + src) * O_ + lane) * H_];
        a0 = fmaf(p.x, bf2f(hv.x), a0);
        a1 = fmaf(p.y, bf2f(hv.y), a1);
        a2 = fmaf(p.z, bf2f(hv.z), a2);
        a3 = fmaf(p.w, bf2f(hv.w), a3);
    }

    float r = a0 / fmaxf(s0, 1e-16f) + a1 / fmaxf(s1, 1e-16f)
            + a2 / fmaxf(s2, 1e-16f) + a3 / fmaxf(s3, 1e-16f);
    out[((size_t)b * N_ + dst) * O_ + lane] = 0.25f * r + bias[lane];
}

// ---------------------------------------------------------------------------
extern "C" void kernel_launch(void* const* d_in, const int* in_sizes, int n_in,
                              void* d_out, int out_size, void* d_ws, size_t ws_size,
                              hipStream_t stream)
{
    (void)in_sizes; (void)n_in; (void)out_size; (void)ws_size;
    const float* x        = (const float*)d_in[0];
    const int*   ei       = (const int*)d_in[1];     // int64 in ref -> int32 here
    const float* eattr    = (const float*)d_in[2];
    const float* Wsrc     = (const float*)d_in[3];
    const float* att_src  = (const float*)d_in[4];
    const float* att_dst  = (const float*)d_in[5];
    const float* W_edge   = (const float*)d_in[6];
    const float* att_edge = (const float*)d_in[7];
    const float* bias     = (const float*)d_in[8];
    float* out = (float*)d_out;

    // workspace carve-up (16B-aligned chunks)
    char* w = (char*)d_ws;
    auto take = [&](size_t bytes) { char* p = w; w += (bytes + 15) & ~size_t(15); return p; };
    unsigned short* hb   = (unsigned short*)take((size_t)B_ * N_ * O_ * H_ * 2); // 20.48 MB
    float* asrc    = (float*)take((size_t)B_ * N_ * H_ * 4);                     // 640 KB
    float* adst    = (float*)take((size_t)B_ * N_ * H_ * 4);
    float* psorted = (float*)take((size_t)E_ * B_ * H_ * 4);                     // 10.24 MB
    float* c       = (float*)take(4 * 4);
    unsigned short* W1t = (unsigned short*)take((size_t)256 * 128 * 2);          // 64 KB
    unsigned short* W2t = (unsigned short*)take((size_t)256 * 128 * 2);
    float* vsrc    = (float*)take((size_t)128 * 4 * 4);                          // 2 KB
    float* vdst    = (float*)take((size_t)128 * 4 * 4);
    int* deg       = (int*)take((size_t)N_ * 4);
    int* rowptr    = (int*)take((size_t)(N_ + 1) * 4);
    int* cursor    = (int*)take((size_t)N_ * 4);
    int* srcSorted = (int*)take((size_t)E_ * 4);
    int* dstSorted = (int*)take((size_t)E_ * 4);
    float* eaSorted= (float*)take((size_t)E_ * 4);

    hipLaunchKernelGGL(k_init, dim3(40), dim3(256), 0, stream,
                       deg, W_edge, att_edge, c);
    hipLaunchKernelGGL(k_wprep, dim3(128), dim3(256), 0, stream,
                       Wsrc, att_src, att_dst, W1t, W2t, vsrc, vdst);
    hipLaunchKernelGGL(k_gemm, dim3((B_ * N_) / 64), dim3(256), 0, stream,
                       x, W1t, W2t, vsrc, vdst, hb, asrc, adst);
    hipLaunchKernelGGL(k_hist, dim3((E_ + 255) / 256), dim3(256), 0, stream, ei, deg);
    hipLaunchKernelGGL(k_scan, dim3(1), dim3(1024), 0, stream, deg, rowptr, cursor);
    hipLaunchKernelGGL(k_place, dim3((E_ + 255) / 256), dim3(256), 0, stream,
                       ei, eattr, cursor, srcSorted, dstSorted, eaSorted);
    hipLaunchKernelGGL(k_edge, dim3(E_ * B_ / 256), dim3(256), 0, stream,
                       srcSorted, dstSorted, eaSorted, asrc, adst, c, psorted);
    hipLaunchKernelGGL(k_agg, dim3(N_ / 4 * B_), dim3(256), 0, stream,
                       rowptr, srcSorted, psorted, hb, bias, out);
}

// Round 6
// 218.558 us; speedup vs baseline: 3.2082x; 1.1465x over previous
//
#include <hip/hip_runtime.h>
#include <hip/hip_bf16.h>
#include <math.h>

// Problem constants (fixed shapes from the reference)
constexpr int B_  = 4;
constexpr int N_  = 10000;
constexpr int E_  = 160000;
constexpr int D_  = 128;
constexpr int H_  = 4;
constexpr int O_  = 64;
constexpr float NEG_SLOPE = 0.2f;

using short8 = __attribute__((ext_vector_type(8))) short;
using f32x4  = __attribute__((ext_vector_type(4))) float;

static __device__ __forceinline__ unsigned short f2bf(float f) {
    unsigned u = __float_as_uint(f);
    u += 0x7fffu + ((u >> 16) & 1u);           // RN-even
    return (unsigned short)(u >> 16);
}
static __device__ __forceinline__ float bf2f(unsigned short h) {
    return __uint_as_float((unsigned)h << 16);
}

// ---------------------------------------------------------------------------
// k_prep (merged init+wprep), 128 blocks:
//   block d: W1t/W2t bf16 split of Wsrc[d][h][o] -> [c][d], c = o*4+h;
//            v_src[d][h], v_dst[d][h] row reductions.
//   all blocks: grid-stride zero of deg[]; block 0: c[h].
// ---------------------------------------------------------------------------
__global__ __launch_bounds__(256) void k_prep(
    const float* __restrict__ Wsrc, const float* __restrict__ att_src,
    const float* __restrict__ att_dst,
    const float* __restrict__ W_edge, const float* __restrict__ att_edge,
    unsigned short* __restrict__ W1t, unsigned short* __restrict__ W2t,
    float* __restrict__ vsrc, float* __restrict__ vdst,
    int* __restrict__ deg, float* __restrict__ c)
{
    const int d = blockIdx.x;
    const int t = threadIdx.x;
    const int h = t >> 6;

    for (int i = d * 256 + t; i < N_; i += 128 * 256) deg[i] = 0;

    const float wv = Wsrc[(size_t)d * 256 + t];
    const unsigned short w1 = f2bf(wv);
    const unsigned short w2 = f2bf(wv - bf2f(w1));
    const int cc = ((t & 63) << 2) | h;      // o*4 + head
    W1t[(size_t)cc * 128 + d] = w1;
    W2t[(size_t)cc * 128 + d] = w2;

    float vs = wv * att_src[t];
    float vd = wv * att_dst[t];
#pragma unroll
    for (int off = 32; off > 0; off >>= 1) {
        vs += __shfl_down(vs, off, 64);
        vd += __shfl_down(vd, off, 64);
    }
    if ((t & 63) == 0) {
        vsrc[d * 4 + h] = vs;
        vdst[d * 4 + h] = vd;
    }

    if (d == 0) {
        float v = W_edge[t] * att_edge[t];
#pragma unroll
        for (int off = 32; off > 0; off >>= 1) v += __shfl_down(v, off, 64);
        if ((t & 63) == 0) c[h] = v;
    }
}

// ---------------------------------------------------------------------------
// k_gemm (MFMA): rows = flat b*N+n (40000), cols c = o*4+head (256), K = 128.
// Split-precision bf16: h = x1@W1 + x1@W2 + x2@W1 (fp32-accurate). Epilogue
// computes exact a_src/a_dst = x . v_{src,dst}. 64 rows/block, 4 waves.
// ---------------------------------------------------------------------------
__global__ __launch_bounds__(256) void k_gemm(
    const float* __restrict__ x,
    const unsigned short* __restrict__ W1t, const unsigned short* __restrict__ W2t,
    const float* __restrict__ vsrc, const float* __restrict__ vdst,
    unsigned short* __restrict__ hbw, float* __restrict__ asrc, float* __restrict__ adst)
{
    constexpr int APAD = 136;                // ushort stride (128+8): conflict-safe
    __shared__ unsigned short A1[64 * APAD];
    __shared__ unsigned short A2[64 * APAD];
    __shared__ float4 vsL[128];
    __shared__ float4 vdL[128];

    const int t = threadIdx.x;
    const int w = t >> 6;                    // wave 0..3
    const int lane = t & 63;
    const int i = lane & 15;
    const int q = lane >> 4;
    const size_t rowbase = (size_t)blockIdx.x * 64;

    {
        const float4* xg = (const float4*)(x + rowbase * D_);
#pragma unroll
        for (int it = 0; it < 8; ++it) {
            const int idx = it * 256 + t;    // 2048 float4 = 64 rows x 32
            const int row = idx >> 5;
            const int c4  = idx & 31;
            float4 xv = xg[idx];
            ushort4 h1, h2;
            h1.x = f2bf(xv.x); h2.x = f2bf(xv.x - bf2f(h1.x));
            h1.y = f2bf(xv.y); h2.y = f2bf(xv.y - bf2f(h1.y));
            h1.z = f2bf(xv.z); h2.z = f2bf(xv.z - bf2f(h1.z));
            h1.w = f2bf(xv.w); h2.w = f2bf(xv.w - bf2f(h1.w));
            *(ushort4*)&A1[row * APAD + c4 * 4] = h1;
            *(ushort4*)&A2[row * APAD + c4 * 4] = h2;
        }
        if (t < 128) vsL[t] = ((const float4*)vsrc)[t];
        else         vdL[t - 128] = ((const float4*)vdst)[t - 128];
    }
    __syncthreads();

    f32x4 acc[16];
#pragma unroll
    for (int ct = 0; ct < 16; ++ct) acc[ct] = (f32x4){0.f, 0.f, 0.f, 0.f};

#pragma unroll
    for (int ks = 0; ks < 4; ++ks) {
        const int aoff = (w * 16 + i) * APAD + ks * 32 + q * 8;
        short8 a1 = *(const short8*)&A1[aoff];
        short8 a2 = *(const short8*)&A2[aoff];
#pragma unroll
        for (int ct = 0; ct < 16; ++ct) {
            const size_t boff = (size_t)(ct * 16 + i) * 128 + ks * 32 + q * 8;
            short8 b1 = *(const short8*)&W1t[boff];
            short8 b2 = *(const short8*)&W2t[boff];
            acc[ct] = __builtin_amdgcn_mfma_f32_16x16x32_bf16(a1, b1, acc[ct], 0, 0, 0);
            acc[ct] = __builtin_amdgcn_mfma_f32_16x16x32_bf16(a2, b1, acc[ct], 0, 0, 0);
            acc[ct] = __builtin_amdgcn_mfma_f32_16x16x32_bf16(a1, b2, acc[ct], 0, 0, 0);
        }
    }

    {   // exact a_src/a_dst from (A1+A2) . v
        const int row_l = w * 16 + i;
        float s0 = 0, s1 = 0, s2 = 0, s3 = 0, d0 = 0, d1 = 0, d2 = 0, d3 = 0;
#pragma unroll 8
        for (int dd = 0; dd < 32; ++dd) {
            const int d = q * 32 + dd;
            const float xv = bf2f(A1[row_l * APAD + d]) + bf2f(A2[row_l * APAD + d]);
            float4 vs = vsL[d], vd = vdL[d];
            s0 = fmaf(xv, vs.x, s0); s1 = fmaf(xv, vs.y, s1);
            s2 = fmaf(xv, vs.z, s2); s3 = fmaf(xv, vs.w, s3);
            d0 = fmaf(xv, vd.x, d0); d1 = fmaf(xv, vd.y, d1);
            d2 = fmaf(xv, vd.z, d2); d3 = fmaf(xv, vd.w, d3);
        }
#pragma unroll
        for (int off = 32; off >= 16; off >>= 1) {
            s0 += __shfl_down(s0, off, 64); s1 += __shfl_down(s1, off, 64);
            s2 += __shfl_down(s2, off, 64); s3 += __shfl_down(s3, off, 64);
            d0 += __shfl_down(d0, off, 64); d1 += __shfl_down(d1, off, 64);
            d2 += __shfl_down(d2, off, 64); d3 += __shfl_down(d3, off, 64);
        }
        if (q == 0) {
            const size_t rg = rowbase + row_l;
            *(float4*)&asrc[rg * 4] = make_float4(s0, s1, s2, s3);
            *(float4*)&adst[rg * 4] = make_float4(d0, d1, d2, d3);
        }
    }

#pragma unroll
    for (int ct = 0; ct < 16; ++ct) {
#pragma unroll
        for (int r = 0; r < 4; ++r) {
            const size_t rg = rowbase + w * 16 + q * 4 + r;
            hbw[rg * 256 + ct * 16 + i] = f2bf(acc[ct][r]);
        }
    }
}

// ---------------------------------------------------------------------------
// k_hist: deg[dst]++ per edge
// ---------------------------------------------------------------------------
__global__ __launch_bounds__(256) void k_hist(const int* __restrict__ ei,
                                              int* __restrict__ deg)
{
    const int e = blockIdx.x * 256 + threadIdx.x;
    if (e < E_) atomicAdd(&deg[ei[E_ + e]], 1);
}

// ---------------------------------------------------------------------------
// k_scan: single-block exclusive prefix sum (shfl-based)
// ---------------------------------------------------------------------------
__global__ __launch_bounds__(1024) void k_scan(const int* __restrict__ deg,
                                               int* __restrict__ rowptr,
                                               int* __restrict__ cursor)
{
    __shared__ int wsum[16];
    __shared__ int wexcl[16];
    __shared__ int btot;
    const int t = threadIdx.x, wv = t >> 6, ln = t & 63;
    int carry = 0;
    for (int c0 = 0; c0 < N_; c0 += 1024) {
        const int idx = c0 + t;
        const int v = (idx < N_) ? deg[idx] : 0;
        int incl = v;
#pragma unroll
        for (int off = 1; off < 64; off <<= 1) {
            int u = __shfl_up(incl, off, 64);
            if (ln >= off) incl += u;
        }
        if (ln == 63) wsum[wv] = incl;
        __syncthreads();
        if (wv == 0) {
            int s = (ln < 16) ? wsum[ln] : 0;
            int si = s;
#pragma unroll
            for (int off = 1; off < 16; off <<= 1) {
                int u = __shfl_up(si, off, 64);
                if (ln >= off) si += u;
            }
            if (ln < 16) wexcl[ln] = si - s;
            if (ln == 15) btot = si;
        }
        __syncthreads();
        const int excl = carry + wexcl[wv] + incl - v;
        if (idx < N_) { rowptr[idx] = excl; cursor[idx] = excl; }
        carry += btot;
        __syncthreads();
    }
    if (t == 0) rowptr[N_] = carry;
}

// ---------------------------------------------------------------------------
// k_place: counting-sort edges by dst; payload packed as int2{src, ea_bits}
// ---------------------------------------------------------------------------
__global__ __launch_bounds__(256) void k_place(
    const int* __restrict__ ei, const float* __restrict__ eattr,
    int* __restrict__ cursor, int2* __restrict__ srcea)
{
    const int e = blockIdx.x * 256 + threadIdx.x;
    if (e >= E_) return;
    const int dst = ei[E_ + e];
    const int pos = atomicAdd(&cursor[dst], 1);
    srcea[pos] = make_int2(ei[e], __float_as_int(eattr[e]));
}

// ---------------------------------------------------------------------------
// k_agg (fused edge+aggregate): one wave per (dst,b).
//   Chunk of <=64 edges: lane j owns edge start+j — coalesced int2 load,
//   asrc[src] float4 gather (L2-resident), computes its own p[4] = exp(leaky).
//   Inner loop broadcasts (src,p) via shfl; only VMEM op is the independent
//   coalesced 512B hb-row gather -> deep pipelining. Non-atomic out write.
// ---------------------------------------------------------------------------
__global__ __launch_bounds__(256) void k_agg(
    const int* __restrict__ rowptr, const int2* __restrict__ srcea,
    const float* __restrict__ asrc, const float* __restrict__ adst,
    const float* __restrict__ cvec, const unsigned short* __restrict__ hbu,
    const float* __restrict__ bias, float* __restrict__ out)
{
    const int b    = blockIdx.x & 3;
    const int g    = blockIdx.x >> 2;
    const int wave = threadIdx.x >> 6;
    const int lane = threadIdx.x & 63;
    const int dst  = g * 4 + wave;

    const int start = rowptr[dst];
    const int end   = rowptr[dst + 1];

    const float4 ad = *(const float4*)&adst[((size_t)b * N_ + dst) * 4];
    const float4 cc = *(const float4*)cvec;

    float a0 = 0.f, a1 = 0.f, a2 = 0.f, a3 = 0.f;
    float s0 = 0.f, s1 = 0.f, s2 = 0.f, s3 = 0.f;

    for (int c0 = start; c0 < end; c0 += 64) {
        const int jl = c0 + lane;
        const bool valid = jl < end;
        const int2 rec = srcea[valid ? jl : (E_ - 1)];
        const int   srcl = rec.x;
        const float ea   = __int_as_float(rec.y);
        const float4 as = *(const float4*)&asrc[((size_t)b * N_ + srcl) * 4];
        float4 al;
        al.x = as.x + ad.x + ea * cc.x;
        al.y = as.y + ad.y + ea * cc.y;
        al.z = as.z + ad.z + ea * cc.z;
        al.w = as.w + ad.w + ea * cc.w;
        al.x = al.x > 0.f ? al.x : NEG_SLOPE * al.x;
        al.y = al.y > 0.f ? al.y : NEG_SLOPE * al.y;
        al.z = al.z > 0.f ? al.z : NEG_SLOPE * al.z;
        al.w = al.w > 0.f ? al.w : NEG_SLOPE * al.w;
        float px = valid ? __expf(al.x) : 0.f;
        float py = valid ? __expf(al.y) : 0.f;
        float pz = valid ? __expf(al.z) : 0.f;
        float pw = valid ? __expf(al.w) : 0.f;

        const int cnt = min(64, end - c0);
        for (int j = 0; j < cnt; ++j) {
            const int   src = __shfl(srcl, j, 64);
            const float qx  = __shfl(px, j, 64);
            const float qy  = __shfl(py, j, 64);
            const float qz  = __shfl(pz, j, 64);
            const float qw  = __shfl(pw, j, 64);
            s0 += qx; s1 += qy; s2 += qz; s3 += qw;
            const ushort4 hv = *(const ushort4*)&hbu[(((size_t)b * N_ + src) * O_ + lane) * H_];
            a0 = fmaf(qx, bf2f(hv.x), a0);
            a1 = fmaf(qy, bf2f(hv.y), a1);
            a2 = fmaf(qz, bf2f(hv.z), a2);
            a3 = fmaf(qw, bf2f(hv.w), a3);
        }
    }

    const float r = a0 / fmaxf(s0, 1e-16f) + a1 / fmaxf(s1, 1e-16f)
                  + a2 / fmaxf(s2, 1e-16f) + a3 / fmaxf(s3, 1e-16f);
    out[((size_t)b * N_ + dst) * O_ + lane] = 0.25f * r + bias[lane];
}

// ---------------------------------------------------------------------------
extern "C" void kernel_launch(void* const* d_in, const int* in_sizes, int n_in,
                              void* d_out, int out_size, void* d_ws, size_t ws_size,
                              hipStream_t stream)
{
    (void)in_sizes; (void)n_in; (void)out_size; (void)ws_size;
    const float* x        = (const float*)d_in[0];
    const int*   ei       = (const int*)d_in[1];     // int64 in ref -> int32 here
    const float* eattr    = (const float*)d_in[2];
    const float* Wsrc     = (const float*)d_in[3];
    const float* att_src  = (const float*)d_in[4];
    const float* att_dst  = (const float*)d_in[5];
    const float* W_edge   = (const float*)d_in[6];
    const float* att_edge = (const float*)d_in[7];
    const float* bias     = (const float*)d_in[8];
    float* out = (float*)d_out;

    // workspace carve-up (16B-aligned chunks)
    char* w = (char*)d_ws;
    auto take = [&](size_t bytes) { char* p = w; w += (bytes + 15) & ~size_t(15); return p; };
    unsigned short* hb   = (unsigned short*)take((size_t)B_ * N_ * O_ * H_ * 2); // 20.48 MB
    float* asrc    = (float*)take((size_t)B_ * N_ * H_ * 4);                     // 640 KB
    float* adst    = (float*)take((size_t)B_ * N_ * H_ * 4);
    float* c       = (float*)take(4 * 4);
    unsigned short* W1t = (unsigned short*)take((size_t)256 * 128 * 2);          // 64 KB
    unsigned short* W2t = (unsigned short*)take((size_t)256 * 128 * 2);
    float* vsrc    = (float*)take((size_t)128 * 4 * 4);                          // 2 KB
    float* vdst    = (float*)take((size_t)128 * 4 * 4);
    int* deg       = (int*)take((size_t)N_ * 4);
    int* rowptr    = (int*)take((size_t)(N_ + 1) * 4);
    int* cursor    = (int*)take((size_t)N_ * 4);
    int2* srcea    = (int2*)take((size_t)E_ * 8);                                // 1.28 MB

    hipLaunchKernelGGL(k_prep, dim3(128), dim3(256), 0, stream,
                       Wsrc, att_src, att_dst, W_edge, att_edge,
                       W1t, W2t, vsrc, vdst, deg, c);
    hipLaunchKernelGGL(k_gemm, dim3((B_ * N_) / 64), dim3(256), 0, stream,
                       x, W1t, W2t, vsrc, vdst, hb, asrc, adst);
    hipLaunchKernelGGL(k_hist, dim3((E_ + 255) / 256), dim3(256), 0, stream, ei, deg);
    hipLaunchKernelGGL(k_scan, dim3(1), dim3(1024), 0, stream, deg, rowptr, cursor);
    hipLaunchKernelGGL(k_place, dim3((E_ + 255) / 256), dim3(256), 0, stream,
                       ei, eattr, cursor, srcea);
    hipLaunchKernelGGL(k_agg, dim3(N_ / 4 * B_), dim3(256), 0, stream,
                       rowptr, srcea, asrc, adst, c, hb, bias, out);
}

// Round 7
// 193.270 us; speedup vs baseline: 3.6280x; 1.1308x over previous
//
#include <hip/hip_runtime.h>
#include <hip/hip_bf16.h>
#include <math.h>

// Problem constants (fixed shapes from the reference)
constexpr int B_  = 4;
constexpr int N_  = 10000;
constexpr int E_  = 160000;
constexpr int D_  = 128;
constexpr int H_  = 4;
constexpr int O_  = 64;
constexpr float NEG_SLOPE = 0.2f;

using short8 = __attribute__((ext_vector_type(8))) short;
using f32x4  = __attribute__((ext_vector_type(4))) float;

static __device__ __forceinline__ unsigned short f2bf(float f) {
    unsigned u = __float_as_uint(f);
    u += 0x7fffu + ((u >> 16) & 1u);           // RN-even
    return (unsigned short)(u >> 16);
}
static __device__ __forceinline__ float bf2f(unsigned short h) {
    return __uint_as_float((unsigned)h << 16);
}

// ---------------------------------------------------------------------------
// k_prep (merged init+wprep), 128 blocks:
//   block d: W1t/W2t bf16 split of Wsrc[d][h][o] -> [c][d], c = o*4+h;
//            v_src[d][h], v_dst[d][h] row reductions.
//   all blocks: grid-stride zero of deg[]; block 0: c[h].
// ---------------------------------------------------------------------------
__global__ __launch_bounds__(256) void k_prep(
    const float* __restrict__ Wsrc, const float* __restrict__ att_src,
    const float* __restrict__ att_dst,
    const float* __restrict__ W_edge, const float* __restrict__ att_edge,
    unsigned short* __restrict__ W1t, unsigned short* __restrict__ W2t,
    float* __restrict__ vsrc, float* __restrict__ vdst,
    int* __restrict__ deg, float* __restrict__ c)
{
    const int d = blockIdx.x;
    const int t = threadIdx.x;
    const int h = t >> 6;

    for (int i = d * 256 + t; i < N_; i += 128 * 256) deg[i] = 0;

    const float wv = Wsrc[(size_t)d * 256 + t];
    const unsigned short w1 = f2bf(wv);
    const unsigned short w2 = f2bf(wv - bf2f(w1));
    const int cc = ((t & 63) << 2) | h;      // o*4 + head
    W1t[(size_t)cc * 128 + d] = w1;
    W2t[(size_t)cc * 128 + d] = w2;

    float vs = wv * att_src[t];
    float vd = wv * att_dst[t];
#pragma unroll
    for (int off = 32; off > 0; off >>= 1) {
        vs += __shfl_down(vs, off, 64);
        vd += __shfl_down(vd, off, 64);
    }
    if ((t & 63) == 0) {
        vsrc[d * 4 + h] = vs;
        vdst[d * 4 + h] = vd;
    }

    if (d == 0) {
        float v = W_edge[t] * att_edge[t];
#pragma unroll
        for (int off = 32; off > 0; off >>= 1) v += __shfl_down(v, off, 64);
        if ((t & 63) == 0) c[h] = v;
    }
}

// ---------------------------------------------------------------------------
// k_gemm (MFMA): rows = flat b*N+n (40000), cols c = o*4+head (256), K = 128.
// 32 rows/block (1250 blocks for occupancy). Wave w owns 4 ct (64 cols) x
// both 16-row tiles: B fragments batched into registers per ks (8 loads in
// flight), reused across 2 row tiles -> B-load:MFMA = 1:3.
// Split-precision bf16: h = x1@W1 + x1@W2 + x2@W1 (fp32-accurate).
// Epilogue: exact a_src/a_dst = x . v_{src,dst}; bf16 h store.
// ---------------------------------------------------------------------------
__global__ __launch_bounds__(256) void k_gemm(
    const float* __restrict__ x,
    const unsigned short* __restrict__ W1t, const unsigned short* __restrict__ W2t,
    const float* __restrict__ vsrc, const float* __restrict__ vdst,
    unsigned short* __restrict__ hbw, float* __restrict__ asrc, float* __restrict__ adst)
{
    constexpr int ROWS = 32;
    constexpr int APAD = 136;                // ushort stride (128+8)
    __shared__ unsigned short A1[ROWS * APAD];   // 8.7 KB
    __shared__ unsigned short A2[ROWS * APAD];   // 8.7 KB
    __shared__ float4 vsL[128];                  // 2 KB
    __shared__ float4 vdL[128];                  // 2 KB

    const int t = threadIdx.x;
    const int w = t >> 6;                    // wave = ct-group 0..3
    const int lane = t & 63;
    const int i = lane & 15;
    const int q = lane >> 4;
    const size_t rowbase = (size_t)blockIdx.x * ROWS;

    // ---- stage x -> bf16 hi/lo in LDS (+ v vectors) ----
    {
        const float4* xg = (const float4*)(x + rowbase * D_);
#pragma unroll
        for (int it = 0; it < 4; ++it) {
            const int idx = it * 256 + t;    // 1024 float4 = 32 rows x 32
            const int row = idx >> 5;
            const int c4  = idx & 31;
            float4 xv = xg[idx];
            ushort4 h1, h2;
            h1.x = f2bf(xv.x); h2.x = f2bf(xv.x - bf2f(h1.x));
            h1.y = f2bf(xv.y); h2.y = f2bf(xv.y - bf2f(h1.y));
            h1.z = f2bf(xv.z); h2.z = f2bf(xv.z - bf2f(h1.z));
            h1.w = f2bf(xv.w); h2.w = f2bf(xv.w - bf2f(h1.w));
            *(ushort4*)&A1[row * APAD + c4 * 4] = h1;
            *(ushort4*)&A2[row * APAD + c4 * 4] = h2;
        }
        if (t < 128) vsL[t] = ((const float4*)vsrc)[t];
        else         vdL[t - 128] = ((const float4*)vdst)[t - 128];
    }
    __syncthreads();

    // ---- MFMA main loop ----
    f32x4 acc[2][4];                         // [row-tile][ctl]
#pragma unroll
    for (int tl = 0; tl < 2; ++tl)
#pragma unroll
        for (int ctl = 0; ctl < 4; ++ctl) acc[tl][ctl] = (f32x4){0.f, 0.f, 0.f, 0.f};

#pragma unroll
    for (int ks = 0; ks < 4; ++ks) {
        const int a0off = i * APAD + ks * 32 + q * 8;
        const int a1off = (16 + i) * APAD + ks * 32 + q * 8;
        short8 a1t0 = *(const short8*)&A1[a0off];
        short8 a2t0 = *(const short8*)&A2[a0off];
        short8 a1t1 = *(const short8*)&A1[a1off];
        short8 a2t1 = *(const short8*)&A2[a1off];

        short8 b1[4], b2[4];                 // batch all 8 B-loads (ILP)
#pragma unroll
        for (int ctl = 0; ctl < 4; ++ctl) {
            const size_t boff = (size_t)((w * 4 + ctl) * 16 + i) * 128 + ks * 32 + q * 8;
            b1[ctl] = *(const short8*)&W1t[boff];
            b2[ctl] = *(const short8*)&W2t[boff];
        }
#pragma unroll
        for (int ctl = 0; ctl < 4; ++ctl) {
            acc[0][ctl] = __builtin_amdgcn_mfma_f32_16x16x32_bf16(a1t0, b1[ctl], acc[0][ctl], 0, 0, 0);
            acc[0][ctl] = __builtin_amdgcn_mfma_f32_16x16x32_bf16(a2t0, b1[ctl], acc[0][ctl], 0, 0, 0);
            acc[0][ctl] = __builtin_amdgcn_mfma_f32_16x16x32_bf16(a1t0, b2[ctl], acc[0][ctl], 0, 0, 0);
            acc[1][ctl] = __builtin_amdgcn_mfma_f32_16x16x32_bf16(a1t1, b1[ctl], acc[1][ctl], 0, 0, 0);
            acc[1][ctl] = __builtin_amdgcn_mfma_f32_16x16x32_bf16(a2t1, b1[ctl], acc[1][ctl], 0, 0, 0);
            acc[1][ctl] = __builtin_amdgcn_mfma_f32_16x16x32_bf16(a1t1, b2[ctl], acc[1][ctl], 0, 0, 0);
        }
    }

    // ---- epilogue 1: exact a_src/a_dst from (A1+A2) . v ----
    // wave w owns rows 8w..8w+7; lane = r*8+g: row 8w+r, d-slice g*16..g*16+15
    {
        const int r = lane >> 3, g = lane & 7;
        const int row_l = w * 8 + r;
        float s0 = 0, s1 = 0, s2 = 0, s3 = 0, d0 = 0, d1 = 0, d2 = 0, d3 = 0;
#pragma unroll
        for (int dd4 = 0; dd4 < 4; ++dd4) {
            const int db = g * 16 + dd4 * 4;
            ushort4 u1 = *(const ushort4*)&A1[row_l * APAD + db];
            ushort4 u2 = *(const ushort4*)&A2[row_l * APAD + db];
            const float xv0 = bf2f(u1.x) + bf2f(u2.x);
            const float xv1 = bf2f(u1.y) + bf2f(u2.y);
            const float xv2 = bf2f(u1.z) + bf2f(u2.z);
            const float xv3 = bf2f(u1.w) + bf2f(u2.w);
            float4 vsa = vsL[db + 0], vda = vdL[db + 0];
            float4 vsb = vsL[db + 1], vdb = vdL[db + 1];
            float4 vsc = vsL[db + 2], vdc = vdL[db + 2];
            float4 vsd = vsL[db + 3], vdd = vdL[db + 3];
            s0 = fmaf(xv0, vsa.x, s0); s1 = fmaf(xv0, vsa.y, s1);
            s2 = fmaf(xv0, vsa.z, s2); s3 = fmaf(xv0, vsa.w, s3);
            d0 = fmaf(xv0, vda.x, d0); d1 = fmaf(xv0, vda.y, d1);
            d2 = fmaf(xv0, vda.z, d2); d3 = fmaf(xv0, vda.w, d3);
            s0 = fmaf(xv1, vsb.x, s0); s1 = fmaf(xv1, vsb.y, s1);
            s2 = fmaf(xv1, vsb.z, s2); s3 = fmaf(xv1, vsb.w, s3);
            d0 = fmaf(xv1, vdb.x, d0); d1 = fmaf(xv1, vdb.y, d1);
            d2 = fmaf(xv1, vdb.z, d2); d3 = fmaf(xv1, vdb.w, d3);
            s0 = fmaf(xv2, vsc.x, s0); s1 = fmaf(xv2, vsc.y, s1);
            s2 = fmaf(xv2, vsc.z, s2); s3 = fmaf(xv2, vsc.w, s3);
            d0 = fmaf(xv2, vdc.x, d0); d1 = fmaf(xv2, vdc.y, d1);
            d2 = fmaf(xv2, vdc.z, d2); d3 = fmaf(xv2, vdc.w, d3);
            s0 = fmaf(xv3, vsd.x, s0); s1 = fmaf(xv3, vsd.y, s1);
            s2 = fmaf(xv3, vsd.z, s2); s3 = fmaf(xv3, vsd.w, s3);
            d0 = fmaf(xv3, vdd.x, d0); d1 = fmaf(xv3, vdd.y, d1);
            d2 = fmaf(xv3, vdd.z, d2); d3 = fmaf(xv3, vdd.w, d3);
        }
#pragma unroll
        for (int off = 4; off > 0; off >>= 1) {   // reduce over g (8 lanes)
            s0 += __shfl_down(s0, off, 64); s1 += __shfl_down(s1, off, 64);
            s2 += __shfl_down(s2, off, 64); s3 += __shfl_down(s3, off, 64);
            d0 += __shfl_down(d0, off, 64); d1 += __shfl_down(d1, off, 64);
            d2 += __shfl_down(d2, off, 64); d3 += __shfl_down(d3, off, 64);
        }
        if (g == 0) {
            const size_t rg = rowbase + row_l;
            *(float4*)&asrc[rg * 4] = make_float4(s0, s1, s2, s3);
            *(float4*)&adst[rg * 4] = make_float4(d0, d1, d2, d3);
        }
    }

    // ---- epilogue 2: store hb bf16. C/D: col=ct*16+i, row=tile*16+q*4+r ----
#pragma unroll
    for (int tl = 0; tl < 2; ++tl) {
#pragma unroll
        for (int ctl = 0; ctl < 4; ++ctl) {
#pragma unroll
            for (int r = 0; r < 4; ++r) {
                const size_t rg = rowbase + tl * 16 + q * 4 + r;
                hbw[rg * 256 + (w * 4 + ctl) * 16 + i] = f2bf(acc[tl][ctl][r]);
            }
        }
    }
}

// ---------------------------------------------------------------------------
// k_hist: deg[dst]++ per edge
// ---------------------------------------------------------------------------
__global__ __launch_bounds__(256) void k_hist(const int* __restrict__ ei,
                                              int* __restrict__ deg)
{
    const int e = blockIdx.x * 256 + threadIdx.x;
    if (e < E_) atomicAdd(&deg[ei[E_ + e]], 1);
}

// ---------------------------------------------------------------------------
// k_scan: single-block exclusive prefix sum (shfl-based)
// ---------------------------------------------------------------------------
__global__ __launch_bounds__(1024) void k_scan(const int* __restrict__ deg,
                                               int* __restrict__ rowptr,
                                               int* __restrict__ cursor)
{
    __shared__ int wsum[16];
    __shared__ int wexcl[16];
    __shared__ int btot;
    const int t = threadIdx.x, wv = t >> 6, ln = t & 63;
    int carry = 0;
    for (int c0 = 0; c0 < N_; c0 += 1024) {
        const int idx = c0 + t;
        const int v = (idx < N_) ? deg[idx] : 0;
        int incl = v;
#pragma unroll
        for (int off = 1; off < 64; off <<= 1) {
            int u = __shfl_up(incl, off, 64);
            if (ln >= off) incl += u;
        }
        if (ln == 63) wsum[wv] = incl;
        __syncthreads();
        if (wv == 0) {
            int s = (ln < 16) ? wsum[ln] : 0;
            int si = s;
#pragma unroll
            for (int off = 1; off < 16; off <<= 1) {
                int u = __shfl_up(si, off, 64);
                if (ln >= off) si += u;
            }
            if (ln < 16) wexcl[ln] = si - s;
            if (ln == 15) btot = si;
        }
        __syncthreads();
        const int excl = carry + wexcl[wv] + incl - v;
        if (idx < N_) { rowptr[idx] = excl; cursor[idx] = excl; }
        carry += btot;
        __syncthreads();
    }
    if (t == 0) rowptr[N_] = carry;
}

// ---------------------------------------------------------------------------
// k_place: counting-sort edges by dst; payload packed as int2{src, ea_bits}
// ---------------------------------------------------------------------------
__global__ __launch_bounds__(256) void k_place(
    const int* __restrict__ ei, const float* __restrict__ eattr,
    int* __restrict__ cursor, int2* __restrict__ srcea)
{
    const int e = blockIdx.x * 256 + threadIdx.x;
    if (e >= E_) return;
    const int dst = ei[E_ + e];
    const int pos = atomicAdd(&cursor[dst], 1);
    srcea[pos] = make_int2(ei[e], __float_as_int(eattr[e]));
}

// ---------------------------------------------------------------------------
// k_agg (fused edge+aggregate): one wave per (dst,b).
//   Chunk of <=64 edges: lane j owns edge start+j — coalesced int2 load,
//   asrc[src] float4 gather (L2-resident), computes its own p[4] = exp(leaky).
//   Inner loop broadcasts (src,p) via shfl; only VMEM op is the independent
//   coalesced 512B hb-row gather -> deep pipelining. Non-atomic out write.
// ---------------------------------------------------------------------------
__global__ __launch_bounds__(256) void k_agg(
    const int* __restrict__ rowptr, const int2* __restrict__ srcea,
    const float* __restrict__ asrc, const float* __restrict__ adst,
    const float* __restrict__ cvec, const unsigned short* __restrict__ hbu,
    const float* __restrict__ bias, float* __restrict__ out)
{
    const int b    = blockIdx.x & 3;
    const int g    = blockIdx.x >> 2;
    const int wave = threadIdx.x >> 6;
    const int lane = threadIdx.x & 63;
    const int dst  = g * 4 + wave;

    const int start = rowptr[dst];
    const int end   = rowptr[dst + 1];

    const float4 ad = *(const float4*)&adst[((size_t)b * N_ + dst) * 4];
    const float4 cc = *(const float4*)cvec;

    float a0 = 0.f, a1 = 0.f, a2 = 0.f, a3 = 0.f;
    float s0 = 0.f, s1 = 0.f, s2 = 0.f, s3 = 0.f;

    for (int c0 = start; c0 < end; c0 += 64) {
        const int jl = c0 + lane;
        const bool valid = jl < end;
        const int2 rec = srcea[valid ? jl : (E_ - 1)];
        const int   srcl = rec.x;
        const float ea   = __int_as_float(rec.y);
        const float4 as = *(const float4*)&asrc[((size_t)b * N_ + srcl) * 4];
        float4 al;
        al.x = as.x + ad.x + ea * cc.x;
        al.y = as.y + ad.y + ea * cc.y;
        al.z = as.z + ad.z + ea * cc.z;
        al.w = as.w + ad.w + ea * cc.w;
        al.x = al.x > 0.f ? al.x : NEG_SLOPE * al.x;
        al.y = al.y > 0.f ? al.y : NEG_SLOPE * al.y;
        al.z = al.z > 0.f ? al.z : NEG_SLOPE * al.z;
        al.w = al.w > 0.f ? al.w : NEG_SLOPE * al.w;
        float px = valid ? __expf(al.x) : 0.f;
        float py = valid ? __expf(al.y) : 0.f;
        float pz = valid ? __expf(al.z) : 0.f;
        float pw = valid ? __expf(al.w) : 0.f;

        const int cnt = min(64, end - c0);
        for (int j = 0; j < cnt; ++j) {
            const int   src = __shfl(srcl, j, 64);
            const float qx  = __shfl(px, j, 64);
            const float qy  = __shfl(py, j, 64);
            const float qz  = __shfl(pz, j, 64);
            const float qw  = __shfl(pw, j, 64);
            s0 += qx; s1 += qy; s2 += qz; s3 += qw;
            const ushort4 hv = *(const ushort4*)&hbu[(((size_t)b * N_ + src) * O_ + lane) * H_];
            a0 = fmaf(qx, bf2f(hv.x), a0);
            a1 = fmaf(qy, bf2f(hv.y), a1);
            a2 = fmaf(qz, bf2f(hv.z), a2);
            a3 = fmaf(qw, bf2f(hv.w), a3);
        }
    }

    const float r = a0 / fmaxf(s0, 1e-16f) + a1 / fmaxf(s1, 1e-16f)
                  + a2 / fmaxf(s2, 1e-16f) + a3 / fmaxf(s3, 1e-16f);
    out[((size_t)b * N_ + dst) * O_ + lane] = 0.25f * r + bias[lane];
}

// ---------------------------------------------------------------------------
extern "C" void kernel_launch(void* const* d_in, const int* in_sizes, int n_in,
                              void* d_out, int out_size, void* d_ws, size_t ws_size,
                              hipStream_t stream)
{
    (void)in_sizes; (void)n_in; (void)out_size; (void)ws_size;
    const float* x        = (const float*)d_in[0];
    const int*   ei       = (const int*)d_in[1];     // int64 in ref -> int32 here
    const float* eattr    = (const float*)d_in[2];
    const float* Wsrc     = (const float*)d_in[3];
    const float* att_src  = (const float*)d_in[4];
    const float* att_dst  = (const float*)d_in[5];
    const float* W_edge   = (const float*)d_in[6];
    const float* att_edge = (const float*)d_in[7];
    const float* bias     = (const float*)d_in[8];
    float* out = (float*)d_out;

    // workspace carve-up (16B-aligned chunks)
    char* w = (char*)d_ws;
    auto take = [&](size_t bytes) { char* p = w; w += (bytes + 15) & ~size_t(15); return p; };
    unsigned short* hb   = (unsigned short*)take((size_t)B_ * N_ * O_ * H_ * 2); // 20.48 MB
    float* asrc    = (float*)take((size_t)B_ * N_ * H_ * 4);                     // 640 KB
    float* adst    = (float*)take((size_t)B_ * N_ * H_ * 4);
    float* c       = (float*)take(4 * 4);
    unsigned short* W1t = (unsigned short*)take((size_t)256 * 128 * 2);          // 64 KB
    unsigned short* W2t = (unsigned short*)take((size_t)256 * 128 * 2);
    float* vsrc    = (float*)take((size_t)128 * 4 * 4);                          // 2 KB
    float* vdst    = (float*)take((size_t)128 * 4 * 4);
    int* deg       = (int*)take((size_t)N_ * 4);
    int* rowptr    = (int*)take((size_t)(N_ + 1) * 4);
    int* cursor    = (int*)take((size_t)N_ * 4);
    int2* srcea    = (int2*)take((size_t)E_ * 8);                                // 1.28 MB

    hipLaunchKernelGGL(k_prep, dim3(128), dim3(256), 0, stream,
                       Wsrc, att_src, att_dst, W_edge, att_edge,
                       W1t, W2t, vsrc, vdst, deg, c);
    hipLaunchKernelGGL(k_gemm, dim3((B_ * N_) / 32), dim3(256), 0, stream,
                       x, W1t, W2t, vsrc, vdst, hb, asrc, adst);
    hipLaunchKernelGGL(k_hist, dim3((E_ + 255) / 256), dim3(256), 0, stream, ei, deg);
    hipLaunchKernelGGL(k_scan, dim3(1), dim3(1024), 0, stream, deg, rowptr, cursor);
    hipLaunchKernelGGL(k_place, dim3((E_ + 255) / 256), dim3(256), 0, stream,
                       ei, eattr, cursor, srcea);
    hipLaunchKernelGGL(k_agg, dim3(N_ / 4 * B_), dim3(256), 0, stream,
                       rowptr, srcea, asrc, adst, c, hb, bias, out);
}

// Round 8
// 180.844 us; speedup vs baseline: 3.8773x; 1.0687x over previous
//
#include <hip/hip_runtime.h>
#include <hip/hip_bf16.h>
#include <math.h>

// Problem constants (fixed shapes from the reference)
constexpr int B_  = 4;
constexpr int N_  = 10000;
constexpr int E_  = 160000;
constexpr int D_  = 128;
constexpr int H_  = 4;
constexpr int O_  = 64;
constexpr float NEG_SLOPE = 0.2f;

using short8 = __attribute__((ext_vector_type(8))) short;
using f32x4  = __attribute__((ext_vector_type(4))) float;

static __device__ __forceinline__ unsigned short f2bf(float f) {
    unsigned u = __float_as_uint(f);
    u += 0x7fffu + ((u >> 16) & 1u);           // RN-even
    return (unsigned short)(u >> 16);
}
static __device__ __forceinline__ float bf2f(unsigned short h) {
    return __uint_as_float((unsigned)h << 16);
}

// ---------------------------------------------------------------------------
// k_prep (merged init+wprep), 128 blocks:
//   block d: W1t/W2t bf16 split of Wsrc[d][h][o] -> [c][d], c = o*4+h;
//            v_src[d][h], v_dst[d][h] row reductions.
//   all blocks: grid-stride zero of deg[]; block 0: c[h].
// ---------------------------------------------------------------------------
__global__ __launch_bounds__(256) void k_prep(
    const float* __restrict__ Wsrc, const float* __restrict__ att_src,
    const float* __restrict__ att_dst,
    const float* __restrict__ W_edge, const float* __restrict__ att_edge,
    unsigned short* __restrict__ W1t, unsigned short* __restrict__ W2t,
    float* __restrict__ vsrc, float* __restrict__ vdst,
    int* __restrict__ deg, float* __restrict__ c)
{
    const int d = blockIdx.x;
    const int t = threadIdx.x;
    const int h = t >> 6;

    for (int i = d * 256 + t; i < N_; i += 128 * 256) deg[i] = 0;

    const float wv = Wsrc[(size_t)d * 256 + t];
    const unsigned short w1 = f2bf(wv);
    const unsigned short w2 = f2bf(wv - bf2f(w1));
    const int cc = ((t & 63) << 2) | h;      // o*4 + head
    W1t[(size_t)cc * 128 + d] = w1;
    W2t[(size_t)cc * 128 + d] = w2;

    float vs = wv * att_src[t];
    float vd = wv * att_dst[t];
#pragma unroll
    for (int off = 32; off > 0; off >>= 1) {
        vs += __shfl_down(vs, off, 64);
        vd += __shfl_down(vd, off, 64);
    }
    if ((t & 63) == 0) {
        vsrc[d * 4 + h] = vs;
        vdst[d * 4 + h] = vd;
    }

    if (d == 0) {
        float v = W_edge[t] * att_edge[t];
#pragma unroll
        for (int off = 32; off > 0; off >>= 1) v += __shfl_down(v, off, 64);
        if ((t & 63) == 0) c[h] = v;
    }
}

// ---------------------------------------------------------------------------
// k_gemm (MFMA): rows = flat b*N+n (40000), cols c = o*4+head (256), K = 128.
// 32 rows/block (1250 blocks). Wave w owns 4 ct (64 cols) x both 16-row
// tiles; B fragments batched into registers per ks, reused across 2 tiles.
// Split-precision bf16: h = x1@W1 + x1@W2 + x2@W1 (fp32-accurate).
// ---------------------------------------------------------------------------
__global__ __launch_bounds__(256) void k_gemm(
    const float* __restrict__ x,
    const unsigned short* __restrict__ W1t, const unsigned short* __restrict__ W2t,
    const float* __restrict__ vsrc, const float* __restrict__ vdst,
    unsigned short* __restrict__ hbw, float* __restrict__ asrc, float* __restrict__ adst)
{
    constexpr int ROWS = 32;
    constexpr int APAD = 136;                // ushort stride (128+8)
    __shared__ unsigned short A1[ROWS * APAD];
    __shared__ unsigned short A2[ROWS * APAD];
    __shared__ float4 vsL[128];
    __shared__ float4 vdL[128];

    const int t = threadIdx.x;
    const int w = t >> 6;
    const int lane = t & 63;
    const int i = lane & 15;
    const int q = lane >> 4;
    const size_t rowbase = (size_t)blockIdx.x * ROWS;

    {
        const float4* xg = (const float4*)(x + rowbase * D_);
#pragma unroll
        for (int it = 0; it < 4; ++it) {
            const int idx = it * 256 + t;
            const int row = idx >> 5;
            const int c4  = idx & 31;
            float4 xv = xg[idx];
            ushort4 h1, h2;
            h1.x = f2bf(xv.x); h2.x = f2bf(xv.x - bf2f(h1.x));
            h1.y = f2bf(xv.y); h2.y = f2bf(xv.y - bf2f(h1.y));
            h1.z = f2bf(xv.z); h2.z = f2bf(xv.z - bf2f(h1.z));
            h1.w = f2bf(xv.w); h2.w = f2bf(xv.w - bf2f(h1.w));
            *(ushort4*)&A1[row * APAD + c4 * 4] = h1;
            *(ushort4*)&A2[row * APAD + c4 * 4] = h2;
        }
        if (t < 128) vsL[t] = ((const float4*)vsrc)[t];
        else         vdL[t - 128] = ((const float4*)vdst)[t - 128];
    }
    __syncthreads();

    f32x4 acc[2][4];
#pragma unroll
    for (int tl = 0; tl < 2; ++tl)
#pragma unroll
        for (int ctl = 0; ctl < 4; ++ctl) acc[tl][ctl] = (f32x4){0.f, 0.f, 0.f, 0.f};

#pragma unroll
    for (int ks = 0; ks < 4; ++ks) {
        const int a0off = i * APAD + ks * 32 + q * 8;
        const int a1off = (16 + i) * APAD + ks * 32 + q * 8;
        short8 a1t0 = *(const short8*)&A1[a0off];
        short8 a2t0 = *(const short8*)&A2[a0off];
        short8 a1t1 = *(const short8*)&A1[a1off];
        short8 a2t1 = *(const short8*)&A2[a1off];

        short8 b1[4], b2[4];
#pragma unroll
        for (int ctl = 0; ctl < 4; ++ctl) {
            const size_t boff = (size_t)((w * 4 + ctl) * 16 + i) * 128 + ks * 32 + q * 8;
            b1[ctl] = *(const short8*)&W1t[boff];
            b2[ctl] = *(const short8*)&W2t[boff];
        }
#pragma unroll
        for (int ctl = 0; ctl < 4; ++ctl) {
            acc[0][ctl] = __builtin_amdgcn_mfma_f32_16x16x32_bf16(a1t0, b1[ctl], acc[0][ctl], 0, 0, 0);
            acc[0][ctl] = __builtin_amdgcn_mfma_f32_16x16x32_bf16(a2t0, b1[ctl], acc[0][ctl], 0, 0, 0);
            acc[0][ctl] = __builtin_amdgcn_mfma_f32_16x16x32_bf16(a1t0, b2[ctl], acc[0][ctl], 0, 0, 0);
            acc[1][ctl] = __builtin_amdgcn_mfma_f32_16x16x32_bf16(a1t1, b1[ctl], acc[1][ctl], 0, 0, 0);
            acc[1][ctl] = __builtin_amdgcn_mfma_f32_16x16x32_bf16(a2t1, b1[ctl], acc[1][ctl], 0, 0, 0);
            acc[1][ctl] = __builtin_amdgcn_mfma_f32_16x16x32_bf16(a1t1, b2[ctl], acc[1][ctl], 0, 0, 0);
        }
    }

    {   // exact a_src/a_dst from (A1+A2) . v
        const int r = lane >> 3, g = lane & 7;
        const int row_l = w * 8 + r;
        float s0 = 0, s1 = 0, s2 = 0, s3 = 0, d0 = 0, d1 = 0, d2 = 0, d3 = 0;
#pragma unroll
        for (int dd4 = 0; dd4 < 4; ++dd4) {
            const int db = g * 16 + dd4 * 4;
            ushort4 u1 = *(const ushort4*)&A1[row_l * APAD + db];
            ushort4 u2 = *(const ushort4*)&A2[row_l * APAD + db];
            const float xv0 = bf2f(u1.x) + bf2f(u2.x);
            const float xv1 = bf2f(u1.y) + bf2f(u2.y);
            const float xv2 = bf2f(u1.z) + bf2f(u2.z);
            const float xv3 = bf2f(u1.w) + bf2f(u2.w);
            float4 vsa = vsL[db + 0], vda = vdL[db + 0];
            float4 vsb = vsL[db + 1], vdb = vdL[db + 1];
            float4 vsc = vsL[db + 2], vdc = vdL[db + 2];
            float4 vsd = vsL[db + 3], vdd = vdL[db + 3];
            s0 = fmaf(xv0, vsa.x, s0); s1 = fmaf(xv0, vsa.y, s1);
            s2 = fmaf(xv0, vsa.z, s2); s3 = fmaf(xv0, vsa.w, s3);
            d0 = fmaf(xv0, vda.x, d0); d1 = fmaf(xv0, vda.y, d1);
            d2 = fmaf(xv0, vda.z, d2); d3 = fmaf(xv0, vda.w, d3);
            s0 = fmaf(xv1, vsb.x, s0); s1 = fmaf(xv1, vsb.y, s1);
            s2 = fmaf(xv1, vsb.z, s2); s3 = fmaf(xv1, vsb.w, s3);
            d0 = fmaf(xv1, vdb.x, d0); d1 = fmaf(xv1, vdb.y, d1);
            d2 = fmaf(xv1, vdb.z, d2); d3 = fmaf(xv1, vdb.w, d3);
            s0 = fmaf(xv2, vsc.x, s0); s1 = fmaf(xv2, vsc.y, s1);
            s2 = fmaf(xv2, vsc.z, s2); s3 = fmaf(xv2, vsc.w, s3);
            d0 = fmaf(xv2, vdc.x, d0); d1 = fmaf(xv2, vdc.y, d1);
            d2 = fmaf(xv2, vdc.z, d2); d3 = fmaf(xv2, vdc.w, d3);
            s0 = fmaf(xv3, vsd.x, s0); s1 = fmaf(xv3, vsd.y, s1);
            s2 = fmaf(xv3, vsd.z, s2); s3 = fmaf(xv3, vsd.w, s3);
            d0 = fmaf(xv3, vdd.x, d0); d1 = fmaf(xv3, vdd.y, d1);
            d2 = fmaf(xv3, vdd.z, d2); d3 = fmaf(xv3, vdd.w, d3);
        }
#pragma unroll
        for (int off = 4; off > 0; off >>= 1) {
            s0 += __shfl_down(s0, off, 64); s1 += __shfl_down(s1, off, 64);
            s2 += __shfl_down(s2, off, 64); s3 += __shfl_down(s3, off, 64);
            d0 += __shfl_down(d0, off, 64); d1 += __shfl_down(d1, off, 64);
            d2 += __shfl_down(d2, off, 64); d3 += __shfl_down(d3, off, 64);
        }
        if (g == 0) {
            const size_t rg = rowbase + row_l;
            *(float4*)&asrc[rg * 4] = make_float4(s0, s1, s2, s3);
            *(float4*)&adst[rg * 4] = make_float4(d0, d1, d2, d3);
        }
    }

#pragma unroll
    for (int tl = 0; tl < 2; ++tl) {
#pragma unroll
        for (int ctl = 0; ctl < 4; ++ctl) {
#pragma unroll
            for (int r = 0; r < 4; ++r) {
                const size_t rg = rowbase + tl * 16 + q * 4 + r;
                hbw[rg * 256 + (w * 4 + ctl) * 16 + i] = f2bf(acc[tl][ctl][r]);
            }
        }
    }
}

// ---------------------------------------------------------------------------
// k_hist: deg[dst]++ per edge
// ---------------------------------------------------------------------------
__global__ __launch_bounds__(256) void k_hist(const int* __restrict__ ei,
                                              int* __restrict__ deg)
{
    const int e = blockIdx.x * 256 + threadIdx.x;
    if (e < E_) atomicAdd(&deg[ei[E_ + e]], 1);
}

// ---------------------------------------------------------------------------
// k_scan: single-block exclusive prefix sum (shfl-based)
// ---------------------------------------------------------------------------
__global__ __launch_bounds__(1024) void k_scan(const int* __restrict__ deg,
                                               int* __restrict__ rowptr,
                                               int* __restrict__ cursor)
{
    __shared__ int wsum[16];
    __shared__ int wexcl[16];
    __shared__ int btot;
    const int t = threadIdx.x, wv = t >> 6, ln = t & 63;
    int carry = 0;
    for (int c0 = 0; c0 < N_; c0 += 1024) {
        const int idx = c0 + t;
        const int v = (idx < N_) ? deg[idx] : 0;
        int incl = v;
#pragma unroll
        for (int off = 1; off < 64; off <<= 1) {
            int u = __shfl_up(incl, off, 64);
            if (ln >= off) incl += u;
        }
        if (ln == 63) wsum[wv] = incl;
        __syncthreads();
        if (wv == 0) {
            int s = (ln < 16) ? wsum[ln] : 0;
            int si = s;
#pragma unroll
            for (int off = 1; off < 16; off <<= 1) {
                int u = __shfl_up(si, off, 64);
                if (ln >= off) si += u;
            }
            if (ln < 16) wexcl[ln] = si - s;
            if (ln == 15) btot = si;
        }
        __syncthreads();
        const int excl = carry + wexcl[wv] + incl - v;
        if (idx < N_) { rowptr[idx] = excl; cursor[idx] = excl; }
        carry += btot;
        __syncthreads();
    }
    if (t == 0) rowptr[N_] = carry;
}

// ---------------------------------------------------------------------------
// k_place: counting-sort edges by dst; payload packed as int2{src, ea_bits}
// ---------------------------------------------------------------------------
__global__ __launch_bounds__(256) void k_place(
    const int* __restrict__ ei, const float* __restrict__ eattr,
    int* __restrict__ cursor, int2* __restrict__ srcea)
{
    const int e = blockIdx.x * 256 + threadIdx.x;
    if (e >= E_) return;
    const int dst = ei[E_ + e];
    const int pos = atomicAdd(&cursor[dst], 1);
    srcea[pos] = make_int2(ei[e], __float_as_int(eattr[e]));
}

// ---------------------------------------------------------------------------
// k_agg (fused edge+aggregate): one wave per (dst,b).
//   Chunk phase (lane-parallel over <=64 edges): int2 load, asrc gather,
//   p = exp(leaky), per-lane denominator partials, (p4, hb-row-index) -> LDS.
//   Inner loop: 2 uniform broadcast LDS reads per edge (ds_read_b128+b32),
//   unroll-2 with split accumulators -> 2 independent hb gathers in flight.
//   Denominator reduced once at the end (butterfly). Non-atomic out write.
// ---------------------------------------------------------------------------
__global__ __launch_bounds__(256) void k_agg(
    const int* __restrict__ rowptr, const int2* __restrict__ srcea,
    const float* __restrict__ asrc, const float* __restrict__ adst,
    const float* __restrict__ cvec, const unsigned short* __restrict__ hbu,
    const float* __restrict__ bias, float* __restrict__ out)
{
    __shared__ float pS[4][64][4];       // [wave][j][h]  4 KB
    __shared__ int   baseS[4][64];       // hb row start (ushort idx)  1 KB

    const int b    = blockIdx.x & 3;
    const int g    = blockIdx.x >> 2;
    const int wave = threadIdx.x >> 6;
    const int lane = threadIdx.x & 63;
    const int dst  = g * 4 + wave;

    const int start = rowptr[dst];
    const int end   = rowptr[dst + 1];

    const float4 ad = *(const float4*)&adst[((size_t)b * N_ + dst) * 4];
    const float4 cc = *(const float4*)cvec;

    float x0 = 0.f, x1 = 0.f, x2 = 0.f, x3 = 0.f;   // acc set A
    float y0 = 0.f, y1 = 0.f, y2 = 0.f, y3 = 0.f;   // acc set B
    float q0 = 0.f, q1 = 0.f, q2 = 0.f, q3 = 0.f;   // per-lane denom partials

    for (int c0 = start; c0 < end; c0 += 64) {
        const int jl = c0 + lane;
        const bool valid = jl < end;
        const int2 rec = srcea[valid ? jl : start];
        const int   srcl = rec.x;
        const float ea   = __int_as_float(rec.y);
        const float4 as = *(const float4*)&asrc[((size_t)b * N_ + srcl) * 4];
        float4 al;
        al.x = as.x + ad.x + ea * cc.x;
        al.y = as.y + ad.y + ea * cc.y;
        al.z = as.z + ad.z + ea * cc.z;
        al.w = as.w + ad.w + ea * cc.w;
        al.x = al.x > 0.f ? al.x : NEG_SLOPE * al.x;
        al.y = al.y > 0.f ? al.y : NEG_SLOPE * al.y;
        al.z = al.z > 0.f ? al.z : NEG_SLOPE * al.z;
        al.w = al.w > 0.f ? al.w : NEG_SLOPE * al.w;
        const float px = valid ? __expf(al.x) : 0.f;
        const float py = valid ? __expf(al.y) : 0.f;
        const float pz = valid ? __expf(al.z) : 0.f;
        const float pw = valid ? __expf(al.w) : 0.f;
        q0 += px; q1 += py; q2 += pz; q3 += pw;

        *(float4*)&pS[wave][lane][0] = make_float4(px, py, pz, pw);
        baseS[wave][lane] = (b * N_ + srcl) << 8;    // *256 ushorts per row
        __builtin_amdgcn_wave_barrier();

        const int cnt = min(64, end - c0);
        int j = 0;
        for (; j + 2 <= cnt; j += 2) {
            const float4 p0 = *(const float4*)&pS[wave][j][0];
            const int    r0 = baseS[wave][j];
            const float4 p1 = *(const float4*)&pS[wave][j + 1][0];
            const int    r1 = baseS[wave][j + 1];
            const ushort4 h0 = *(const ushort4*)&hbu[(size_t)r0 + lane * 4];
            const ushort4 h1 = *(const ushort4*)&hbu[(size_t)r1 + lane * 4];
            x0 = fmaf(p0.x, bf2f(h0.x), x0);
            x1 = fmaf(p0.y, bf2f(h0.y), x1);
            x2 = fmaf(p0.z, bf2f(h0.z), x2);
            x3 = fmaf(p0.w, bf2f(h0.w), x3);
            y0 = fmaf(p1.x, bf2f(h1.x), y0);
            y1 = fmaf(p1.y, bf2f(h1.y), y1);
            y2 = fmaf(p1.z, bf2f(h1.z), y2);
            y3 = fmaf(p1.w, bf2f(h1.w), y3);
        }
        if (j < cnt) {
            const float4 p0 = *(const float4*)&pS[wave][j][0];
            const int    r0 = baseS[wave][j];
            const ushort4 h0 = *(const ushort4*)&hbu[(size_t)r0 + lane * 4];
            x0 = fmaf(p0.x, bf2f(h0.x), x0);
            x1 = fmaf(p0.y, bf2f(h0.y), x1);
            x2 = fmaf(p0.z, bf2f(h0.z), x2);
            x3 = fmaf(p0.w, bf2f(h0.w), x3);
        }
        __builtin_amdgcn_wave_barrier();
    }

    // denominator: butterfly reduce-all over lanes
#pragma unroll
    for (int off = 32; off > 0; off >>= 1) {
        q0 += __shfl_xor(q0, off, 64);
        q1 += __shfl_xor(q1, off, 64);
        q2 += __shfl_xor(q2, off, 64);
        q3 += __shfl_xor(q3, off, 64);
    }

    const float r = (x0 + y0) / fmaxf(q0, 1e-16f) + (x1 + y1) / fmaxf(q1, 1e-16f)
                  + (x2 + y2) / fmaxf(q2, 1e-16f) + (x3 + y3) / fmaxf(q3, 1e-16f);
    out[((size_t)b * N_ + dst) * O_ + lane] = 0.25f * r + bias[lane];
}

// ---------------------------------------------------------------------------
extern "C" void kernel_launch(void* const* d_in, const int* in_sizes, int n_in,
                              void* d_out, int out_size, void* d_ws, size_t ws_size,
                              hipStream_t stream)
{
    (void)in_sizes; (void)n_in; (void)out_size; (void)ws_size;
    const float* x        = (const float*)d_in[0];
    const int*   ei       = (const int*)d_in[1];     // int64 in ref -> int32 here
    const float* eattr    = (const float*)d_in[2];
    const float* Wsrc     = (const float*)d_in[3];
    const float* att_src  = (const float*)d_in[4];
    const float* att_dst  = (const float*)d_in[5];
    const float* W_edge   = (const float*)d_in[6];
    const float* att_edge = (const float*)d_in[7];
    const float* bias     = (const float*)d_in[8];
    float* out = (float*)d_out;

    // workspace carve-up (16B-aligned chunks)
    char* w = (char*)d_ws;
    auto take = [&](size_t bytes) { char* p = w; w += (bytes + 15) & ~size_t(15); return p; };
    unsigned short* hb   = (unsigned short*)take((size_t)B_ * N_ * O_ * H_ * 2); // 20.48 MB
    float* asrc    = (float*)take((size_t)B_ * N_ * H_ * 4);                     // 640 KB
    float* adst    = (float*)take((size_t)B_ * N_ * H_ * 4);
    float* c       = (float*)take(4 * 4);
    unsigned short* W1t = (unsigned short*)take((size_t)256 * 128 * 2);          // 64 KB
    unsigned short* W2t = (unsigned short*)take((size_t)256 * 128 * 2);
    float* vsrc    = (float*)take((size_t)128 * 4 * 4);                          // 2 KB
    float* vdst    = (float*)take((size_t)128 * 4 * 4);
    int* deg       = (int*)take((size_t)N_ * 4);
    int* rowptr    = (int*)take((size_t)(N_ + 1) * 4);
    int* cursor    = (int*)take((size_t)N_ * 4);
    int2* srcea    = (int2*)take((size_t)E_ * 8);                                // 1.28 MB

    hipLaunchKernelGGL(k_prep, dim3(128), dim3(256), 0, stream,
                       Wsrc, att_src, att_dst, W_edge, att_edge,
                       W1t, W2t, vsrc, vdst, deg, c);
    hipLaunchKernelGGL(k_gemm, dim3((B_ * N_) / 32), dim3(256), 0, stream,
                       x, W1t, W2t, vsrc, vdst, hb, asrc, adst);
    hipLaunchKernelGGL(k_hist, dim3((E_ + 255) / 256), dim3(256), 0, stream, ei, deg);
    hipLaunchKernelGGL(k_scan, dim3(1), dim3(1024), 0, stream, deg, rowptr, cursor);
    hipLaunchKernelGGL(k_place, dim3((E_ + 255) / 256), dim3(256), 0, stream,
                       ei, eattr, cursor, srcea);
    hipLaunchKernelGGL(k_agg, dim3(N_ / 4 * B_), dim3(256), 0, stream,
                       rowptr, srcea, asrc, adst, c, hb, bias, out);
}